// Round 8
// baseline (784.381 us; speedup 1.0000x reference)
//
#include <hip/hip_runtime.h>
#include <hip/hip_fp16.h>
#include <math.h>

#define NEG_SLOPE 0.2f
#define GAT_EPS 1e-16f

__device__ __forceinline__ float lrelu(float x) { return x > 0.f ? x : NEG_SLOPE * x; }

// ---------------------------------------------------------------------------
// C[M,Ncol] = A[M,K] * B[K,Ncol]; K % 16 == 0, Ncol % 64 == 0. fp32 compute.
// Optionally writes fp32 C and/or fp16 C16 (either may be null).
// ---------------------------------------------------------------------------
__global__ __launch_bounds__(256) void gemm_tiled(
    const float* __restrict__ A, const float* __restrict__ B,
    float* __restrict__ C, __half* __restrict__ C16, int M, int K, int Ncol)
{
    __shared__ float As[16][65];   // [k][m], padded
    __shared__ float Bs[16][64];   // [k][n]

    const int t  = threadIdx.x;
    const int bm = blockIdx.x * 64;
    const int bn = blockIdx.y * 64;
    const int tx = t & 15;   // n
    const int ty = t >> 4;   // m

    float acc[4][4] = {};

    for (int k0 = 0; k0 < K; k0 += 16) {
        {
            const int r  = t >> 2;
            const int kq = (t & 3) * 4;
            float4 v = make_float4(0.f, 0.f, 0.f, 0.f);
            const int row = bm + r;
            if (row < M) v = *(const float4*)(A + (size_t)row * K + k0 + kq);
            As[kq + 0][r] = v.x; As[kq + 1][r] = v.y;
            As[kq + 2][r] = v.z; As[kq + 3][r] = v.w;
        }
        {
            const int k  = t >> 4;
            const int nq = (t & 15) * 4;
            float4 v = *(const float4*)(B + (size_t)(k0 + k) * Ncol + bn + nq);
            *(float4*)(&Bs[k][nq]) = v;
        }
        __syncthreads();

        #pragma unroll
        for (int k = 0; k < 16; ++k) {
            float a[4], b[4];
            #pragma unroll
            for (int i = 0; i < 4; ++i) a[i] = As[k][ty * 4 + i];
            #pragma unroll
            for (int j = 0; j < 4; ++j) b[j] = Bs[k][tx * 4 + j];
            #pragma unroll
            for (int i = 0; i < 4; ++i)
                #pragma unroll
                for (int j = 0; j < 4; ++j)
                    acc[i][j] += a[i] * b[j];
        }
        __syncthreads();
    }

    #pragma unroll
    for (int i = 0; i < 4; ++i) {
        const int row = bm + ty * 4 + i;
        if (row < M) {
            #pragma unroll
            for (int j = 0; j < 4; ++j) {
                const float v = acc[i][j];
                const size_t idx = (size_t)row * Ncol + bn + tx * 4 + j;
                if (C)   C[idx]   = v;
                if (C16) C16[idx] = __float2half_rn(v);
            }
        }
    }
}

// ---------------------------------------------------------------------------
// Per (node, head): alpha_src/dst dot products, fp32 h. H = 4.
// ---------------------------------------------------------------------------
__global__ __launch_bounds__(256) void alpha_kernel(
    const float* __restrict__ h, const float* __restrict__ a_src,
    const float* __restrict__ a_dst, float* __restrict__ as_,
    float* __restrict__ ad_, int N, int HC, int C)
{
    const int i = blockIdx.x * blockDim.x + threadIdx.x;
    if (i >= N * 4) return;
    const int n  = i >> 2;
    const int hh = i & 3;
    const float* hp  = h + (size_t)n * HC + hh * C;
    const float* asp = a_src + hh * C;
    const float* adp = a_dst + hh * C;
    float s1 = 0.f, s2 = 0.f;
    for (int c = 0; c < C; c += 4) {
        const float4 v = *(const float4*)(hp + c);
        const float4 A = *(const float4*)(asp + c);
        const float4 D = *(const float4*)(adp + c);
        s1 += v.x * A.x + v.y * A.y + v.z * A.z + v.w * A.w;
        s2 += v.x * D.x + v.y * D.y + v.z * D.z + v.w * D.w;
    }
    as_[i] = s1;
    ad_[i] = s2;
}

// Same, fp16 h (layer 2; C = 64).
__global__ __launch_bounds__(256) void alpha16_kernel(
    const __half* __restrict__ h, const float* __restrict__ a_src,
    const float* __restrict__ a_dst, float* __restrict__ as_,
    float* __restrict__ ad_, int N, int HC, int C)
{
    const int i = blockIdx.x * blockDim.x + threadIdx.x;
    if (i >= N * 4) return;
    const int n  = i >> 2;
    const int hh = i & 3;
    const __half* hp = h + (size_t)n * HC + hh * C;
    const float* asp = a_src + hh * C;
    const float* adp = a_dst + hh * C;
    float s1 = 0.f, s2 = 0.f;
    for (int c = 0; c < C; c += 2) {
        const float2 f = __half22float2(*(const __half2*)(hp + c));
        s1 += f.x * asp[c] + f.y * asp[c + 1];
        s2 += f.x * adp[c] + f.y * adp[c + 1];
    }
    as_[i] = s1;
    ad_[i] = s2;
}

// ---------------------------------------------------------------------------
// CSR build: zero degrees -> count -> scan -> scatter.
// ---------------------------------------------------------------------------
__global__ __launch_bounds__(256) void zero_kernel(int* __restrict__ p, int n)
{
    const int i = blockIdx.x * 256 + threadIdx.x;
    if (i < n) p[i] = 0;
}

__global__ __launch_bounds__(256) void count_kernel(
    const int* __restrict__ ei, int* __restrict__ deg, int E)
{
    const int e = blockIdx.x * 256 + threadIdx.x;
    if (e < E) atomicAdd(&deg[ei[E + e]], 1);
}

__global__ __launch_bounds__(1024) void scan_kernel(
    const int* __restrict__ deg, int* __restrict__ rp, int N)
{
    __shared__ int sums[1024];
    const int tid  = threadIdx.x;
    const int L    = (N + 1023) >> 10;
    const int base = tid * L;
    int s = 0;
    for (int i = 0; i < L; ++i) {
        const int idx = base + i;
        if (idx < N) s += deg[idx];
    }
    sums[tid] = s;
    __syncthreads();
    for (int off = 1; off < 1024; off <<= 1) {
        const int v = (tid >= off) ? sums[tid - off] : 0;
        __syncthreads();
        sums[tid] += v;
        __syncthreads();
    }
    int run = (tid == 0) ? 0 : sums[tid - 1];
    if (tid == 0) rp[0] = 0;
    for (int i = 0; i < L; ++i) {
        const int idx = base + i;
        if (idx < N) { rp[idx + 1] = run; run += deg[idx]; }
    }
}

__global__ __launch_bounds__(256) void scatter_kernel(
    const int* __restrict__ ei, int* __restrict__ rp, int* __restrict__ col, int E)
{
    const int e = blockIdx.x * 256 + threadIdx.x;
    if (e < E) {
        const int dn  = ei[E + e];
        const int pos = atomicAdd(&rp[dn + 1], 1);
        col[pos] = ei[e];
    }
}

// ---------------------------------------------------------------------------
// Fused softmax + aggregate, layers 0/1 (HC=128, C=32), bias+ReLU epilogue.
// Block per dst node; wave = head. fp16 gather table; fp32 math.
// No max-subtraction (softmax shift-invariant; logits O(+-6), no overflow).
// Per 64-edge chunk: lane j computes att(edge j) in-register; FMA phase
// shfl-broadcasts att/src. 8 chains, half-wave per edge.
// ---------------------------------------------------------------------------
__global__ __launch_bounds__(256) void agg32_kernel(
    const __half* __restrict__ h16, const float* __restrict__ as_,
    const float* __restrict__ ad_, const int* __restrict__ rp,
    const int* __restrict__ col, const float* __restrict__ bias,
    float* __restrict__ out, int N)
{
    const int n    = blockIdx.x;
    const int lane = threadIdx.x & 63;
    const int hh   = threadIdx.x >> 6;
    const int start = rp[n];
    const int d     = rp[n + 1] - start;
    const float adn = ad_[n * 4 + hh];

    const int c  = lane & 31;
    const int eo = lane >> 5;
    float ssum = 0.f;
    float ac0 = 0.f, ac1 = 0.f, ac2 = 0.f, ac3 = 0.f;
    float ac4 = 0.f, ac5 = 0.f, ac6 = 0.f, ac7 = 0.f;

    for (int c0 = 0; c0 < d; c0 += 64) {
        const int len = min(64, d - c0);
        int   sreg = 0;
        float areg = 0.f;
        if (lane < len) {
            sreg = col[start + c0 + lane];
            areg = __expf(lrelu(as_[sreg * 4 + hh] + adn));
        }
        ssum += areg;
        int j = 0;
        for (; j + 16 <= len; j += 16) {
            const int   s0 = __shfl(sreg, j + 0 + eo);
            const int   s1 = __shfl(sreg, j + 2 + eo);
            const int   s2 = __shfl(sreg, j + 4 + eo);
            const int   s3 = __shfl(sreg, j + 6 + eo);
            const int   s4 = __shfl(sreg, j + 8 + eo);
            const int   s5 = __shfl(sreg, j + 10 + eo);
            const int   s6 = __shfl(sreg, j + 12 + eo);
            const int   s7 = __shfl(sreg, j + 14 + eo);
            const float a0 = __shfl(areg, j + 0 + eo);
            const float a1 = __shfl(areg, j + 2 + eo);
            const float a2 = __shfl(areg, j + 4 + eo);
            const float a3 = __shfl(areg, j + 6 + eo);
            const float a4 = __shfl(areg, j + 8 + eo);
            const float a5 = __shfl(areg, j + 10 + eo);
            const float a6 = __shfl(areg, j + 12 + eo);
            const float a7 = __shfl(areg, j + 14 + eo);
            ac0 += a0 * __half2float(h16[(size_t)s0 * 128 + hh * 32 + c]);
            ac1 += a1 * __half2float(h16[(size_t)s1 * 128 + hh * 32 + c]);
            ac2 += a2 * __half2float(h16[(size_t)s2 * 128 + hh * 32 + c]);
            ac3 += a3 * __half2float(h16[(size_t)s3 * 128 + hh * 32 + c]);
            ac4 += a4 * __half2float(h16[(size_t)s4 * 128 + hh * 32 + c]);
            ac5 += a5 * __half2float(h16[(size_t)s5 * 128 + hh * 32 + c]);
            ac6 += a6 * __half2float(h16[(size_t)s6 * 128 + hh * 32 + c]);
            ac7 += a7 * __half2float(h16[(size_t)s7 * 128 + hh * 32 + c]);
        }
        for (; j < len; j += 2) {
            const int e  = j + eo;
            const int q  = min(e, len - 1);
            const int   ss = __shfl(sreg, q);
            const float aa = __shfl(areg, q);
            if (e < len)
                ac0 += aa * __half2float(h16[(size_t)ss * 128 + hh * 32 + c]);
        }
    }

    #pragma unroll
    for (int off = 32; off; off >>= 1) ssum += __shfl_xor(ssum, off);
    float acc = ((ac0 + ac1) + (ac2 + ac3)) + ((ac4 + ac5) + (ac6 + ac7));
    acc += __shfl_xor(acc, 32);
    const float aself = __expf(lrelu(as_[n * 4 + hh] + adn));
    ssum += aself;
    acc  += aself * __half2float(h16[(size_t)n * 128 + hh * 32 + c]);

    if (lane < 32) {
        const float r = acc / (ssum + GAT_EPS) + bias[hh * 32 + c];
        out[(size_t)n * 128 + hh * 32 + c] = fmaxf(r, 0.f);
    }
}

// ---------------------------------------------------------------------------
// Fused softmax + aggregate + head-mean + bias, layer 2 (HC=256, C=64) -> d_out
// fp16 gather table; full wave per edge, 8 chains.
// ---------------------------------------------------------------------------
__global__ __launch_bounds__(256) void agg64_mean_kernel(
    const __half* __restrict__ h16, const float* __restrict__ as_,
    const float* __restrict__ ad_, const int* __restrict__ rp,
    const int* __restrict__ col, const float* __restrict__ b2,
    float* __restrict__ out, int N)
{
    __shared__ float red[4][64];
    const int n    = blockIdx.x;
    const int lane = threadIdx.x & 63;
    const int hh   = threadIdx.x >> 6;
    const int start = rp[n];
    const int d     = rp[n + 1] - start;
    const float adn = ad_[n * 4 + hh];

    float ssum = 0.f;
    float ac0 = 0.f, ac1 = 0.f, ac2 = 0.f, ac3 = 0.f;
    float ac4 = 0.f, ac5 = 0.f, ac6 = 0.f, ac7 = 0.f;

    for (int c0 = 0; c0 < d; c0 += 64) {
        const int len = min(64, d - c0);
        int   sreg = 0;
        float areg = 0.f;
        if (lane < len) {
            sreg = col[start + c0 + lane];
            areg = __expf(lrelu(as_[sreg * 4 + hh] + adn));
        }
        ssum += areg;
        int j = 0;
        for (; j + 8 <= len; j += 8) {
            const int   s0 = __shfl(sreg, j + 0);
            const int   s1 = __shfl(sreg, j + 1);
            const int   s2 = __shfl(sreg, j + 2);
            const int   s3 = __shfl(sreg, j + 3);
            const int   s4 = __shfl(sreg, j + 4);
            const int   s5 = __shfl(sreg, j + 5);
            const int   s6 = __shfl(sreg, j + 6);
            const int   s7 = __shfl(sreg, j + 7);
            const float a0 = __shfl(areg, j + 0);
            const float a1 = __shfl(areg, j + 1);
            const float a2 = __shfl(areg, j + 2);
            const float a3 = __shfl(areg, j + 3);
            const float a4 = __shfl(areg, j + 4);
            const float a5 = __shfl(areg, j + 5);
            const float a6 = __shfl(areg, j + 6);
            const float a7 = __shfl(areg, j + 7);
            ac0 += a0 * __half2float(h16[(size_t)s0 * 256 + hh * 64 + lane]);
            ac1 += a1 * __half2float(h16[(size_t)s1 * 256 + hh * 64 + lane]);
            ac2 += a2 * __half2float(h16[(size_t)s2 * 256 + hh * 64 + lane]);
            ac3 += a3 * __half2float(h16[(size_t)s3 * 256 + hh * 64 + lane]);
            ac4 += a4 * __half2float(h16[(size_t)s4 * 256 + hh * 64 + lane]);
            ac5 += a5 * __half2float(h16[(size_t)s5 * 256 + hh * 64 + lane]);
            ac6 += a6 * __half2float(h16[(size_t)s6 * 256 + hh * 64 + lane]);
            ac7 += a7 * __half2float(h16[(size_t)s7 * 256 + hh * 64 + lane]);
        }
        for (; j < len; ++j) {
            const int   ss = __shfl(sreg, j);
            const float aa = __shfl(areg, j);
            ac0 += aa * __half2float(h16[(size_t)ss * 256 + hh * 64 + lane]);
        }
    }

    #pragma unroll
    for (int off = 32; off; off >>= 1) ssum += __shfl_xor(ssum, off);
    float acc = ((ac0 + ac1) + (ac2 + ac3)) + ((ac4 + ac5) + (ac6 + ac7));
    const float aself = __expf(lrelu(as_[n * 4 + hh] + adn));
    ssum += aself;
    acc  += aself * __half2float(h16[(size_t)n * 256 + hh * 64 + lane]);

    red[hh][lane] = acc / (ssum + GAT_EPS);
    __syncthreads();
    if (threadIdx.x < 64) {
        const int cc = threadIdx.x;
        out[(size_t)n * 64 + cc] =
            0.25f * (red[0][cc] + red[1][cc] + red[2][cc] + red[3][cc]) + b2[cc];
    }
}

// ---------------------------------------------------------------------------
extern "C" void kernel_launch(void* const* d_in, const int* in_sizes, int n_in,
                              void* d_out, int out_size, void* d_ws, size_t ws_size,
                              hipStream_t stream)
{
    const float* x   = (const float*)d_in[0];
    const int*   ei  = (const int*)d_in[1];
    const float* W0  = (const float*)d_in[2];
    const float* aS0 = (const float*)d_in[3];
    const float* aD0 = (const float*)d_in[4];
    const float* b0  = (const float*)d_in[5];
    const float* W1  = (const float*)d_in[6];
    const float* aS1 = (const float*)d_in[7];
    const float* aD1 = (const float*)d_in[8];
    const float* b1  = (const float*)d_in[9];
    const float* W2  = (const float*)d_in[10];
    const float* aS2 = (const float*)d_in[11];
    const float* aD2 = (const float*)d_in[12];
    const float* b2  = (const float*)d_in[13];

    const int N = in_sizes[0] / 128;   // F_in = 128
    const int E = in_sizes[1] / 2;

    // Workspace layout (float units), identical footprint to R7 (~82 MB):
    //   bufA [0,128N)        : fp32 h (layers 0/1)  |  fp16 h2 (layer 2, 256N halfs)
    //   bufA [128N,192N)     : fp16 h (layers 0/1, 128N halfs)  — free upper half
    //   o_buf [256N,384N)    : aggregated fp32 output of layers 0/1
    //   as/ad [384N,392N)
    //   rp/col/deg above
    float* ws     = (float*)d_ws;
    float* bufA   = ws;
    __half* h16a  = (__half*)(ws + (size_t)N * 128);   // layers 0/1 fp16 h
    __half* h2_16 = (__half*)ws;                        // layer 2 fp16 h2 (fp32 unused)
    float* o_buf  = ws + (size_t)N * 256;
    float* as_buf = ws + (size_t)N * 384;
    float* ad_buf = ws + (size_t)N * 388;
    int*   rp     = (int*)(ws + (size_t)N * 392);
    int*   col    = (int*)(ws + (size_t)N * 394);
    int*   deg    = (int*)(ws + (size_t)N * 394) + E;

    const int TB  = 256;
    const int gN  = (N + TB - 1) / TB;
    const int gE  = (E + TB - 1) / TB;
    const int gNH = (N * 4 + TB - 1) / TB;

    // ---- build CSR (dst-sorted adjacency), shared by all 3 layers ----
    zero_kernel<<<gN, TB, 0, stream>>>(deg, N);
    count_kernel<<<gE, TB, 0, stream>>>(ei, deg, E);
    scan_kernel<<<1, 1024, 0, stream>>>(deg, rp, N);
    scatter_kernel<<<gE, TB, 0, stream>>>(ei, rp, col, E);

    // ---- layer 0 ----
    {
        dim3 g((N + 63) / 64, 2);
        gemm_tiled<<<g, TB, 0, stream>>>(x, W0, bufA, h16a, N, 128, 128);
        alpha_kernel<<<gNH, TB, 0, stream>>>(bufA, aS0, aD0, as_buf, ad_buf, N, 128, 32);
        agg32_kernel<<<N, TB, 0, stream>>>(h16a, as_buf, ad_buf, rp, col, b0, o_buf, N);
    }
    // ---- layer 1 ----
    {
        dim3 g((N + 63) / 64, 2);
        gemm_tiled<<<g, TB, 0, stream>>>(o_buf, W1, bufA, h16a, N, 128, 128);
        alpha_kernel<<<gNH, TB, 0, stream>>>(bufA, aS1, aD1, as_buf, ad_buf, N, 128, 32);
        agg32_kernel<<<N, TB, 0, stream>>>(h16a, as_buf, ad_buf, rp, col, b1, o_buf, N);
    }
    // ---- layer 2 (concat=False): fp16-only h2; fused head-mean + bias -> d_out
    {
        dim3 g((N + 63) / 64, 4);
        gemm_tiled<<<g, TB, 0, stream>>>(o_buf, W2, nullptr, h2_16, N, 128, 256);
        alpha16_kernel<<<gNH, TB, 0, stream>>>(h2_16, aS2, aD2, as_buf, ad_buf, N, 256, 64);
        agg64_mean_kernel<<<N, TB, 0, stream>>>(h2_16, as_buf, ad_buf, rp, col, b2, (float*)d_out, N);
    }
}

// Round 9
// 685.059 us; speedup vs baseline: 1.1450x; 1.1450x over previous
//
#include <hip/hip_runtime.h>
#include <hip/hip_fp16.h>
#include <math.h>

#define NEG_SLOPE 0.2f
#define GAT_EPS 1e-16f

__device__ __forceinline__ float lrelu(float x) { return x > 0.f ? x : NEG_SLOPE * x; }

__device__ __forceinline__ void fma_row4(float4& a, float w, uint2 u) {
    const float2 f0 = __half22float2(*(const __half2*)&u.x);
    const float2 f1 = __half22float2(*(const __half2*)&u.y);
    a.x += w * f0.x; a.y += w * f0.y;
    a.z += w * f1.x; a.w += w * f1.y;
}

__device__ __forceinline__ void fma_row2(float2& a, float w, unsigned u) {
    const float2 f = __half22float2(*(const __half2*)&u);
    a.x += w * f.x; a.y += w * f.y;
}

// ---------------------------------------------------------------------------
// C[M,Ncol] = A[M,K] * B[K,Ncol]; K % 16 == 0, Ncol % 64 == 0. fp32 compute.
// Optionally writes fp32 C and/or fp16 C16 (either may be null).
// ---------------------------------------------------------------------------
__global__ __launch_bounds__(256) void gemm_tiled(
    const float* __restrict__ A, const float* __restrict__ B,
    float* __restrict__ C, __half* __restrict__ C16, int M, int K, int Ncol)
{
    __shared__ float As[16][65];
    __shared__ float Bs[16][64];

    const int t  = threadIdx.x;
    const int bm = blockIdx.x * 64;
    const int bn = blockIdx.y * 64;
    const int tx = t & 15;
    const int ty = t >> 4;

    float acc[4][4] = {};

    for (int k0 = 0; k0 < K; k0 += 16) {
        {
            const int r  = t >> 2;
            const int kq = (t & 3) * 4;
            float4 v = make_float4(0.f, 0.f, 0.f, 0.f);
            const int row = bm + r;
            if (row < M) v = *(const float4*)(A + (size_t)row * K + k0 + kq);
            As[kq + 0][r] = v.x; As[kq + 1][r] = v.y;
            As[kq + 2][r] = v.z; As[kq + 3][r] = v.w;
        }
        {
            const int k  = t >> 4;
            const int nq = (t & 15) * 4;
            float4 v = *(const float4*)(B + (size_t)(k0 + k) * Ncol + bn + nq);
            *(float4*)(&Bs[k][nq]) = v;
        }
        __syncthreads();

        #pragma unroll
        for (int k = 0; k < 16; ++k) {
            float a[4], b[4];
            #pragma unroll
            for (int i = 0; i < 4; ++i) a[i] = As[k][ty * 4 + i];
            #pragma unroll
            for (int j = 0; j < 4; ++j) b[j] = Bs[k][tx * 4 + j];
            #pragma unroll
            for (int i = 0; i < 4; ++i)
                #pragma unroll
                for (int j = 0; j < 4; ++j)
                    acc[i][j] += a[i] * b[j];
        }
        __syncthreads();
    }

    #pragma unroll
    for (int i = 0; i < 4; ++i) {
        const int row = bm + ty * 4 + i;
        if (row < M) {
            #pragma unroll
            for (int j = 0; j < 4; ++j) {
                const float v = acc[i][j];
                const size_t idx = (size_t)row * Ncol + bn + tx * 4 + j;
                if (C)   C[idx]   = v;
                if (C16) C16[idx] = __float2half_rn(v);
            }
        }
    }
}

// ---------------------------------------------------------------------------
// Per (node, head): alpha_src/dst dot products, fp32 h. H = 4.
// ---------------------------------------------------------------------------
__global__ __launch_bounds__(256) void alpha_kernel(
    const float* __restrict__ h, const float* __restrict__ a_src,
    const float* __restrict__ a_dst, float* __restrict__ as_,
    float* __restrict__ ad_, int N, int HC, int C)
{
    const int i = blockIdx.x * blockDim.x + threadIdx.x;
    if (i >= N * 4) return;
    const int n  = i >> 2;
    const int hh = i & 3;
    const float* hp  = h + (size_t)n * HC + hh * C;
    const float* asp = a_src + hh * C;
    const float* adp = a_dst + hh * C;
    float s1 = 0.f, s2 = 0.f;
    for (int c = 0; c < C; c += 4) {
        const float4 v = *(const float4*)(hp + c);
        const float4 A = *(const float4*)(asp + c);
        const float4 D = *(const float4*)(adp + c);
        s1 += v.x * A.x + v.y * A.y + v.z * A.z + v.w * A.w;
        s2 += v.x * D.x + v.y * D.y + v.z * D.z + v.w * D.w;
    }
    as_[i] = s1;
    ad_[i] = s2;
}

// Same, fp16 h (layer 2; C = 64).
__global__ __launch_bounds__(256) void alpha16_kernel(
    const __half* __restrict__ h, const float* __restrict__ a_src,
    const float* __restrict__ a_dst, float* __restrict__ as_,
    float* __restrict__ ad_, int N, int HC, int C)
{
    const int i = blockIdx.x * blockDim.x + threadIdx.x;
    if (i >= N * 4) return;
    const int n  = i >> 2;
    const int hh = i & 3;
    const __half* hp = h + (size_t)n * HC + hh * C;
    const float* asp = a_src + hh * C;
    const float* adp = a_dst + hh * C;
    float s1 = 0.f, s2 = 0.f;
    for (int c = 0; c < C; c += 2) {
        const float2 f = __half22float2(*(const __half2*)(hp + c));
        s1 += f.x * asp[c] + f.y * asp[c + 1];
        s2 += f.x * adp[c] + f.y * adp[c + 1];
    }
    as_[i] = s1;
    ad_[i] = s2;
}

// ---------------------------------------------------------------------------
// CSR build: zero degrees -> count -> scan -> scatter.
// ---------------------------------------------------------------------------
__global__ __launch_bounds__(256) void zero_kernel(int* __restrict__ p, int n)
{
    const int i = blockIdx.x * 256 + threadIdx.x;
    if (i < n) p[i] = 0;
}

__global__ __launch_bounds__(256) void count_kernel(
    const int* __restrict__ ei, int* __restrict__ deg, int E)
{
    const int e = blockIdx.x * 256 + threadIdx.x;
    if (e < E) atomicAdd(&deg[ei[E + e]], 1);
}

__global__ __launch_bounds__(1024) void scan_kernel(
    const int* __restrict__ deg, int* __restrict__ rp, int N)
{
    __shared__ int sums[1024];
    const int tid  = threadIdx.x;
    const int L    = (N + 1023) >> 10;
    const int base = tid * L;
    int s = 0;
    for (int i = 0; i < L; ++i) {
        const int idx = base + i;
        if (idx < N) s += deg[idx];
    }
    sums[tid] = s;
    __syncthreads();
    for (int off = 1; off < 1024; off <<= 1) {
        const int v = (tid >= off) ? sums[tid - off] : 0;
        __syncthreads();
        sums[tid] += v;
        __syncthreads();
    }
    int run = (tid == 0) ? 0 : sums[tid - 1];
    if (tid == 0) rp[0] = 0;
    for (int i = 0; i < L; ++i) {
        const int idx = base + i;
        if (idx < N) { rp[idx + 1] = run; run += deg[idx]; }
    }
}

__global__ __launch_bounds__(256) void scatter_kernel(
    const int* __restrict__ ei, int* __restrict__ rp, int* __restrict__ col, int E)
{
    const int e = blockIdx.x * 256 + threadIdx.x;
    if (e < E) {
        const int dn  = ei[E + e];
        const int pos = atomicAdd(&rp[dn + 1], 1);
        col[pos] = ei[e];
    }
}

// ---------------------------------------------------------------------------
// Fused softmax + aggregate, layers 0/1 (HC=128, C=32), bias+ReLU epilogue.
// Block per dst node. Wave w handles edges e ≡ w (mod 4); per edge ONE
// wave-instruction loads the full 128-half row (half2/lane, 256 B).
// Lane covers channels {2*lane, 2*lane+1}; head = lane>>4. att computed
// per lane (redundant x16 per head; we're request-bound, not VALU-bound).
// 4 independent edge chains. Cross-wave combine via LDS; no max-subtract.
// ---------------------------------------------------------------------------
__global__ __launch_bounds__(256) void agg32_kernel(
    const __half* __restrict__ h16, const float* __restrict__ as_,
    const float* __restrict__ ad_, const int* __restrict__ rp,
    const int* __restrict__ col, const float* __restrict__ bias,
    float* __restrict__ out, int N)
{
    __shared__ float2 ared[4][64];
    __shared__ float  sred[4][4];
    const int n    = blockIdx.x;
    const int t    = threadIdx.x;
    const int w    = t >> 6;
    const int lane = t & 63;
    const int head = lane >> 4;
    const int start = rp[n];
    const int d     = rp[n + 1] - start;
    const float adn = ad_[n * 4 + head];

    float ss = 0.f;
    float2 a0 = {0.f, 0.f}, a1 = {0.f, 0.f}, a2 = {0.f, 0.f}, a3 = {0.f, 0.f};

    int e = w;
    for (; e + 12 < d; e += 16) {
        const int s0 = col[start + e];
        const int s1 = col[start + e + 4];
        const int s2 = col[start + e + 8];
        const int s3 = col[start + e + 12];
        const float w0 = __expf(lrelu(as_[s0 * 4 + head] + adn));
        const float w1 = __expf(lrelu(as_[s1 * 4 + head] + adn));
        const float w2 = __expf(lrelu(as_[s2 * 4 + head] + adn));
        const float w3 = __expf(lrelu(as_[s3 * 4 + head] + adn));
        const unsigned u0 = *(const unsigned*)(h16 + (size_t)s0 * 128 + 2 * lane);
        const unsigned u1 = *(const unsigned*)(h16 + (size_t)s1 * 128 + 2 * lane);
        const unsigned u2 = *(const unsigned*)(h16 + (size_t)s2 * 128 + 2 * lane);
        const unsigned u3 = *(const unsigned*)(h16 + (size_t)s3 * 128 + 2 * lane);
        ss += (w0 + w1) + (w2 + w3);
        fma_row2(a0, w0, u0);
        fma_row2(a1, w1, u1);
        fma_row2(a2, w2, u2);
        fma_row2(a3, w3, u3);
    }
    for (; e < d; e += 4) {
        const int s = col[start + e];
        const float wt = __expf(lrelu(as_[s * 4 + head] + adn));
        const unsigned u = *(const unsigned*)(h16 + (size_t)s * 128 + 2 * lane);
        ss += wt;
        fma_row2(a0, wt, u);
    }
    if (w == 0) {   // self-loop, counted exactly once
        const float wt = __expf(lrelu(as_[n * 4 + head] + adn));
        const unsigned u = *(const unsigned*)(h16 + (size_t)n * 128 + 2 * lane);
        ss += wt;
        fma_row2(a0, wt, u);
    }

    float2 at;
    at.x = (a0.x + a1.x) + (a2.x + a3.x);
    at.y = (a0.y + a1.y) + (a2.y + a3.y);
    ared[w][lane] = at;
    if ((lane & 15) == 0) sred[w][head] = ss;   // identical across the 16 lanes/head
    __syncthreads();

    if (t < 128) {
        const int ch = t;                       // output channel 0..127
        const int hh = ch >> 5;
        const float ssum = sred[0][hh] + sred[1][hh] + sred[2][hh] + sred[3][hh];
        const float* ap0 = (const float*)ared[0];
        const float* ap1 = (const float*)ared[1];
        const float* ap2 = (const float*)ared[2];
        const float* ap3 = (const float*)ared[3];
        const float acc = (ap0[ch] + ap1[ch]) + (ap2[ch] + ap3[ch]);
        const float r = acc / (ssum + GAT_EPS) + bias[ch];
        out[(size_t)n * 128 + ch] = fmaxf(r, 0.f);
    }
}

// ---------------------------------------------------------------------------
// Fused softmax + aggregate + head-mean + bias, layer 2 (HC=256, C=64) -> d_out
// Same structure; half4/lane (8 B) covers the full 256-half row (512 B).
// Lane covers channels {4*lane..4*lane+3}; head = lane>>4.
// ---------------------------------------------------------------------------
__global__ __launch_bounds__(256) void agg64_mean_kernel(
    const __half* __restrict__ h16, const float* __restrict__ as_,
    const float* __restrict__ ad_, const int* __restrict__ rp,
    const int* __restrict__ col, const float* __restrict__ b2,
    float* __restrict__ out, int N)
{
    __shared__ float4 ared[4][64];
    __shared__ float  sred[4][4];
    const int n    = blockIdx.x;
    const int t    = threadIdx.x;
    const int w    = t >> 6;
    const int lane = t & 63;
    const int head = lane >> 4;
    const int start = rp[n];
    const int d     = rp[n + 1] - start;
    const float adn = ad_[n * 4 + head];

    float ss = 0.f;
    float4 a0 = {0,0,0,0}, a1 = {0,0,0,0}, a2 = {0,0,0,0}, a3 = {0,0,0,0};

    int e = w;
    for (; e + 12 < d; e += 16) {
        const int s0 = col[start + e];
        const int s1 = col[start + e + 4];
        const int s2 = col[start + e + 8];
        const int s3 = col[start + e + 12];
        const float w0 = __expf(lrelu(as_[s0 * 4 + head] + adn));
        const float w1 = __expf(lrelu(as_[s1 * 4 + head] + adn));
        const float w2 = __expf(lrelu(as_[s2 * 4 + head] + adn));
        const float w3 = __expf(lrelu(as_[s3 * 4 + head] + adn));
        const uint2 u0 = *(const uint2*)(h16 + (size_t)s0 * 256 + 4 * lane);
        const uint2 u1 = *(const uint2*)(h16 + (size_t)s1 * 256 + 4 * lane);
        const uint2 u2 = *(const uint2*)(h16 + (size_t)s2 * 256 + 4 * lane);
        const uint2 u3 = *(const uint2*)(h16 + (size_t)s3 * 256 + 4 * lane);
        ss += (w0 + w1) + (w2 + w3);
        fma_row4(a0, w0, u0);
        fma_row4(a1, w1, u1);
        fma_row4(a2, w2, u2);
        fma_row4(a3, w3, u3);
    }
    for (; e < d; e += 4) {
        const int s = col[start + e];
        const float wt = __expf(lrelu(as_[s * 4 + head] + adn));
        const uint2 u = *(const uint2*)(h16 + (size_t)s * 256 + 4 * lane);
        ss += wt;
        fma_row4(a0, wt, u);
    }
    if (w == 0) {   // self-loop
        const float wt = __expf(lrelu(as_[n * 4 + head] + adn));
        const uint2 u = *(const uint2*)(h16 + (size_t)n * 256 + 4 * lane);
        ss += wt;
        fma_row4(a0, wt, u);
    }

    float4 at;
    at.x = (a0.x + a1.x) + (a2.x + a3.x);
    at.y = (a0.y + a1.y) + (a2.y + a3.y);
    at.z = (a0.z + a1.z) + (a2.z + a3.z);
    at.w = (a0.w + a1.w) + (a2.w + a3.w);
    ared[w][lane] = at;
    if ((lane & 15) == 0) sred[w][head] = ss;
    __syncthreads();

    if (t < 64) {
        float is[4];
        #pragma unroll
        for (int h = 0; h < 4; ++h)
            is[h] = 1.f / (sred[0][h] + sred[1][h] + sred[2][h] + sred[3][h] + GAT_EPS);
        const float* ap0 = (const float*)ared[0];
        const float* ap1 = (const float*)ared[1];
        const float* ap2 = (const float*)ared[2];
        const float* ap3 = (const float*)ared[3];
        float o = 0.f;
        #pragma unroll
        for (int h = 0; h < 4; ++h) {
            const int ch = h * 64 + t;
            o += ((ap0[ch] + ap1[ch]) + (ap2[ch] + ap3[ch])) * is[h];
        }
        out[(size_t)n * 64 + t] = 0.25f * o + b2[t];
    }
}

// ---------------------------------------------------------------------------
extern "C" void kernel_launch(void* const* d_in, const int* in_sizes, int n_in,
                              void* d_out, int out_size, void* d_ws, size_t ws_size,
                              hipStream_t stream)
{
    const float* x   = (const float*)d_in[0];
    const int*   ei  = (const int*)d_in[1];
    const float* W0  = (const float*)d_in[2];
    const float* aS0 = (const float*)d_in[3];
    const float* aD0 = (const float*)d_in[4];
    const float* b0  = (const float*)d_in[5];
    const float* W1  = (const float*)d_in[6];
    const float* aS1 = (const float*)d_in[7];
    const float* aD1 = (const float*)d_in[8];
    const float* b1  = (const float*)d_in[9];
    const float* W2  = (const float*)d_in[10];
    const float* aS2 = (const float*)d_in[11];
    const float* aD2 = (const float*)d_in[12];
    const float* b2  = (const float*)d_in[13];

    const int N = in_sizes[0] / 128;   // F_in = 128
    const int E = in_sizes[1] / 2;

    // Workspace layout (float units), identical footprint to R8 (~82 MB):
    //   bufA [0,128N)        : fp32 h (layers 0/1)  |  fp16 h2 (layer 2, 256N halfs)
    //   bufA [128N,192N)     : fp16 h (layers 0/1, 128N halfs)
    //   o_buf [256N,384N)    : aggregated fp32 output of layers 0/1
    //   as/ad [384N,392N); rp/col/deg above
    float* ws     = (float*)d_ws;
    float* bufA   = ws;
    __half* h16a  = (__half*)(ws + (size_t)N * 128);
    __half* h2_16 = (__half*)ws;
    float* o_buf  = ws + (size_t)N * 256;
    float* as_buf = ws + (size_t)N * 384;
    float* ad_buf = ws + (size_t)N * 388;
    int*   rp     = (int*)(ws + (size_t)N * 392);
    int*   col    = (int*)(ws + (size_t)N * 394);
    int*   deg    = (int*)(ws + (size_t)N * 394) + E;

    const int TB  = 256;
    const int gN  = (N + TB - 1) / TB;
    const int gE  = (E + TB - 1) / TB;
    const int gNH = (N * 4 + TB - 1) / TB;

    // ---- build CSR (dst-sorted adjacency), shared by all 3 layers ----
    zero_kernel<<<gN, TB, 0, stream>>>(deg, N);
    count_kernel<<<gE, TB, 0, stream>>>(ei, deg, E);
    scan_kernel<<<1, 1024, 0, stream>>>(deg, rp, N);
    scatter_kernel<<<gE, TB, 0, stream>>>(ei, rp, col, E);

    // ---- layer 0 ----
    {
        dim3 g((N + 63) / 64, 2);
        gemm_tiled<<<g, TB, 0, stream>>>(x, W0, bufA, h16a, N, 128, 128);
        alpha_kernel<<<gNH, TB, 0, stream>>>(bufA, aS0, aD0, as_buf, ad_buf, N, 128, 32);
        agg32_kernel<<<N, TB, 0, stream>>>(h16a, as_buf, ad_buf, rp, col, b0, o_buf, N);
    }
    // ---- layer 1 ----
    {
        dim3 g((N + 63) / 64, 2);
        gemm_tiled<<<g, TB, 0, stream>>>(o_buf, W1, bufA, h16a, N, 128, 128);
        alpha_kernel<<<gNH, TB, 0, stream>>>(bufA, aS1, aD1, as_buf, ad_buf, N, 128, 32);
        agg32_kernel<<<N, TB, 0, stream>>>(h16a, as_buf, ad_buf, rp, col, b1, o_buf, N);
    }
    // ---- layer 2 (concat=False): fp16-only h2; fused head-mean + bias -> d_out
    {
        dim3 g((N + 63) / 64, 4);
        gemm_tiled<<<g, TB, 0, stream>>>(o_buf, W2, nullptr, h2_16, N, 128, 256);
        alpha16_kernel<<<gNH, TB, 0, stream>>>(h2_16, aS2, aD2, as_buf, ad_buf, N, 256, 64);
        agg64_mean_kernel<<<N, TB, 0, stream>>>(h2_16, as_buf, ad_buf, rp, col, b2, (float*)d_out, N);
    }
}

// Round 10
// 607.585 us; speedup vs baseline: 1.2910x; 1.1275x over previous
//
#include <hip/hip_runtime.h>
#include <hip/hip_fp16.h>
#include <math.h>

#define NEG_SLOPE 0.2f
#define GAT_EPS 1e-16f

__device__ __forceinline__ float lrelu(float x) { return x > 0.f ? x : NEG_SLOPE * x; }

__device__ __forceinline__ void fma_row4(float4& a, float w, uint2 u) {
    const float2 f0 = __half22float2(*(const __half2*)&u.x);
    const float2 f1 = __half22float2(*(const __half2*)&u.y);
    a.x += w * f0.x; a.y += w * f0.y;
    a.z += w * f1.x; a.w += w * f1.y;
}

__device__ __forceinline__ void fma_row2(float2& a, float w, unsigned u) {
    const float2 f = __half22float2(*(const __half2*)&u);
    a.x += w * f.x; a.y += w * f.y;
}

// ---------------------------------------------------------------------------
// C[M,Ncol] = A[M,K] * B[K,Ncol]; K % 16 == 0, Ncol % 64 == 0. fp32 compute.
// Optionally writes fp32 C and/or fp16 C16 (either may be null).
// ---------------------------------------------------------------------------
__global__ __launch_bounds__(256) void gemm_tiled(
    const float* __restrict__ A, const float* __restrict__ B,
    float* __restrict__ C, __half* __restrict__ C16, int M, int K, int Ncol)
{
    __shared__ float As[16][65];
    __shared__ float Bs[16][64];

    const int t  = threadIdx.x;
    const int bm = blockIdx.x * 64;
    const int bn = blockIdx.y * 64;
    const int tx = t & 15;
    const int ty = t >> 4;

    float acc[4][4] = {};

    for (int k0 = 0; k0 < K; k0 += 16) {
        {
            const int r  = t >> 2;
            const int kq = (t & 3) * 4;
            float4 v = make_float4(0.f, 0.f, 0.f, 0.f);
            const int row = bm + r;
            if (row < M) v = *(const float4*)(A + (size_t)row * K + k0 + kq);
            As[kq + 0][r] = v.x; As[kq + 1][r] = v.y;
            As[kq + 2][r] = v.z; As[kq + 3][r] = v.w;
        }
        {
            const int k  = t >> 4;
            const int nq = (t & 15) * 4;
            float4 v = *(const float4*)(B + (size_t)(k0 + k) * Ncol + bn + nq);
            *(float4*)(&Bs[k][nq]) = v;
        }
        __syncthreads();

        #pragma unroll
        for (int k = 0; k < 16; ++k) {
            float a[4], b[4];
            #pragma unroll
            for (int i = 0; i < 4; ++i) a[i] = As[k][ty * 4 + i];
            #pragma unroll
            for (int j = 0; j < 4; ++j) b[j] = Bs[k][tx * 4 + j];
            #pragma unroll
            for (int i = 0; i < 4; ++i)
                #pragma unroll
                for (int j = 0; j < 4; ++j)
                    acc[i][j] += a[i] * b[j];
        }
        __syncthreads();
    }

    #pragma unroll
    for (int i = 0; i < 4; ++i) {
        const int row = bm + ty * 4 + i;
        if (row < M) {
            #pragma unroll
            for (int j = 0; j < 4; ++j) {
                const float v = acc[i][j];
                const size_t idx = (size_t)row * Ncol + bn + tx * 4 + j;
                if (C)   C[idx]   = v;
                if (C16) C16[idx] = __float2half_rn(v);
            }
        }
    }
}

// ---------------------------------------------------------------------------
// Per (node, head): alpha_src/dst dot products, fp32 h. H = 4.
// ---------------------------------------------------------------------------
__global__ __launch_bounds__(256) void alpha_kernel(
    const float* __restrict__ h, const float* __restrict__ a_src,
    const float* __restrict__ a_dst, float* __restrict__ as_,
    float* __restrict__ ad_, int N, int HC, int C)
{
    const int i = blockIdx.x * blockDim.x + threadIdx.x;
    if (i >= N * 4) return;
    const int n  = i >> 2;
    const int hh = i & 3;
    const float* hp  = h + (size_t)n * HC + hh * C;
    const float* asp = a_src + hh * C;
    const float* adp = a_dst + hh * C;
    float s1 = 0.f, s2 = 0.f;
    for (int c = 0; c < C; c += 4) {
        const float4 v = *(const float4*)(hp + c);
        const float4 A = *(const float4*)(asp + c);
        const float4 D = *(const float4*)(adp + c);
        s1 += v.x * A.x + v.y * A.y + v.z * A.z + v.w * A.w;
        s2 += v.x * D.x + v.y * D.y + v.z * D.z + v.w * D.w;
    }
    as_[i] = s1;
    ad_[i] = s2;
}

// Same, fp16 h (layer 2; C = 64).
__global__ __launch_bounds__(256) void alpha16_kernel(
    const __half* __restrict__ h, const float* __restrict__ a_src,
    const float* __restrict__ a_dst, float* __restrict__ as_,
    float* __restrict__ ad_, int N, int HC, int C)
{
    const int i = blockIdx.x * blockDim.x + threadIdx.x;
    if (i >= N * 4) return;
    const int n  = i >> 2;
    const int hh = i & 3;
    const __half* hp = h + (size_t)n * HC + hh * C;
    const float* asp = a_src + hh * C;
    const float* adp = a_dst + hh * C;
    float s1 = 0.f, s2 = 0.f;
    for (int c = 0; c < C; c += 2) {
        const float2 f = __half22float2(*(const __half2*)(hp + c));
        s1 += f.x * asp[c] + f.y * asp[c + 1];
        s2 += f.x * adp[c] + f.y * adp[c + 1];
    }
    as_[i] = s1;
    ad_[i] = s2;
}

// ---------------------------------------------------------------------------
// CSR build: zero degrees -> count -> hierarchical scan -> scatter.
// ---------------------------------------------------------------------------
__global__ __launch_bounds__(256) void zero_kernel(int* __restrict__ p, int n)
{
    const int i = blockIdx.x * 256 + threadIdx.x;
    if (i < n) p[i] = 0;
}

__global__ __launch_bounds__(256) void count_kernel(
    const int* __restrict__ ei, int* __restrict__ deg, int E)
{
    const int e = blockIdx.x * 256 + threadIdx.x;
    if (e < E) atomicAdd(&deg[ei[E + e]], 1);
}

// bsum[b] = sum of deg[b*1024 .. b*1024+1023]
__global__ __launch_bounds__(256) void scan_part_kernel(
    const int* __restrict__ deg, int* __restrict__ bsum, int N)
{
    __shared__ int red[256];
    const int b = blockIdx.x;
    const int t = threadIdx.x;
    const int base = b * 1024 + t * 4;
    int s = 0;
    #pragma unroll
    for (int i = 0; i < 4; ++i) {
        const int idx = base + i;
        if (idx < N) s += deg[idx];
    }
    red[t] = s;
    __syncthreads();
    for (int off = 128; off; off >>= 1) {
        if (t < off) red[t] += red[t + off];
        __syncthreads();
    }
    if (t == 0) bsum[b] = red[0];
}

// single block: exclusive scan of bsum[0..B), B <= 256
__global__ __launch_bounds__(256) void scan_top_kernel(
    int* __restrict__ bsum, int B)
{
    __shared__ int sh[256];
    const int t = threadIdx.x;
    const int v = (t < B) ? bsum[t] : 0;
    sh[t] = v;
    __syncthreads();
    for (int off = 1; off < 256; off <<= 1) {
        const int u = (t >= off) ? sh[t - off] : 0;
        __syncthreads();
        sh[t] += u;
        __syncthreads();
    }
    if (t < B) bsum[t] = sh[t] - v;   // exclusive
}

// rp[0]=0; rp[idx+1] = bsum[b] + local exclusive prefix at idx
// (same shifted semantics the scatter trick needs)
__global__ __launch_bounds__(256) void scan_out_kernel(
    const int* __restrict__ deg, const int* __restrict__ bsum,
    int* __restrict__ rp, int N)
{
    __shared__ int red[256];
    const int b = blockIdx.x;
    const int t = threadIdx.x;
    const int base = b * 1024 + t * 4;
    int v[4]; int s = 0;
    #pragma unroll
    for (int i = 0; i < 4; ++i) {
        const int idx = base + i;
        v[i] = (idx < N) ? deg[idx] : 0;
        s += v[i];
    }
    red[t] = s;
    __syncthreads();
    for (int off = 1; off < 256; off <<= 1) {
        const int u = (t >= off) ? red[t - off] : 0;
        __syncthreads();
        red[t] += u;
        __syncthreads();
    }
    int run = bsum[b] + ((t > 0) ? red[t - 1] : 0);
    if (b == 0 && t == 0) rp[0] = 0;
    #pragma unroll
    for (int i = 0; i < 4; ++i) {
        const int idx = base + i;
        if (idx < N) { rp[idx + 1] = run; run += v[i]; }
    }
}

__global__ __launch_bounds__(256) void scatter_kernel(
    const int* __restrict__ ei, int* __restrict__ rp, int* __restrict__ col, int E)
{
    const int e = blockIdx.x * 256 + threadIdx.x;
    if (e < E) {
        const int dn  = ei[E + e];
        const int pos = atomicAdd(&rp[dn + 1], 1);
        col[pos] = ei[e];
    }
}

// ---------------------------------------------------------------------------
// Fused softmax + aggregate, layers 0/1 (HC=128, C=32), bias+ReLU epilogue.
// Block per dst node. Wave w handles edges e ≡ w (mod 4); per edge ONE
// wave-instruction loads the full 128-half row (half2/lane, 256 B).
// ---------------------------------------------------------------------------
__global__ __launch_bounds__(256) void agg32_kernel(
    const __half* __restrict__ h16, const float* __restrict__ as_,
    const float* __restrict__ ad_, const int* __restrict__ rp,
    const int* __restrict__ col, const float* __restrict__ bias,
    float* __restrict__ out, int N)
{
    __shared__ float2 ared[4][64];
    __shared__ float  sred[4][4];
    const int n    = blockIdx.x;
    const int t    = threadIdx.x;
    const int w    = t >> 6;
    const int lane = t & 63;
    const int head = lane >> 4;
    const int start = rp[n];
    const int d     = rp[n + 1] - start;
    const float adn = ad_[n * 4 + head];

    float ss = 0.f;
    float2 a0 = {0.f, 0.f}, a1 = {0.f, 0.f}, a2 = {0.f, 0.f}, a3 = {0.f, 0.f};

    int e = w;
    for (; e + 12 < d; e += 16) {
        const int s0 = col[start + e];
        const int s1 = col[start + e + 4];
        const int s2 = col[start + e + 8];
        const int s3 = col[start + e + 12];
        const float w0 = __expf(lrelu(as_[s0 * 4 + head] + adn));
        const float w1 = __expf(lrelu(as_[s1 * 4 + head] + adn));
        const float w2 = __expf(lrelu(as_[s2 * 4 + head] + adn));
        const float w3 = __expf(lrelu(as_[s3 * 4 + head] + adn));
        const unsigned u0 = *(const unsigned*)(h16 + (size_t)s0 * 128 + 2 * lane);
        const unsigned u1 = *(const unsigned*)(h16 + (size_t)s1 * 128 + 2 * lane);
        const unsigned u2 = *(const unsigned*)(h16 + (size_t)s2 * 128 + 2 * lane);
        const unsigned u3 = *(const unsigned*)(h16 + (size_t)s3 * 128 + 2 * lane);
        ss += (w0 + w1) + (w2 + w3);
        fma_row2(a0, w0, u0);
        fma_row2(a1, w1, u1);
        fma_row2(a2, w2, u2);
        fma_row2(a3, w3, u3);
    }
    for (; e < d; e += 4) {
        const int s = col[start + e];
        const float wt = __expf(lrelu(as_[s * 4 + head] + adn));
        const unsigned u = *(const unsigned*)(h16 + (size_t)s * 128 + 2 * lane);
        ss += wt;
        fma_row2(a0, wt, u);
    }
    if (w == 0) {   // self-loop, counted exactly once
        const float wt = __expf(lrelu(as_[n * 4 + head] + adn));
        const unsigned u = *(const unsigned*)(h16 + (size_t)n * 128 + 2 * lane);
        ss += wt;
        fma_row2(a0, wt, u);
    }

    float2 at;
    at.x = (a0.x + a1.x) + (a2.x + a3.x);
    at.y = (a0.y + a1.y) + (a2.y + a3.y);
    ared[w][lane] = at;
    if ((lane & 15) == 0) sred[w][head] = ss;
    __syncthreads();

    if (t < 128) {
        const int ch = t;
        const int hh = ch >> 5;
        const float ssum = sred[0][hh] + sred[1][hh] + sred[2][hh] + sred[3][hh];
        const float* ap0 = (const float*)ared[0];
        const float* ap1 = (const float*)ared[1];
        const float* ap2 = (const float*)ared[2];
        const float* ap3 = (const float*)ared[3];
        const float acc = (ap0[ch] + ap1[ch]) + (ap2[ch] + ap3[ch]);
        const float r = acc / (ssum + GAT_EPS) + bias[ch];
        out[(size_t)n * 128 + ch] = fmaxf(r, 0.f);
    }
}

// ---------------------------------------------------------------------------
// Fused softmax + aggregate + head-mean + bias, layer 2 (HC=256, C=64) -> d_out
// ---------------------------------------------------------------------------
__global__ __launch_bounds__(256) void agg64_mean_kernel(
    const __half* __restrict__ h16, const float* __restrict__ as_,
    const float* __restrict__ ad_, const int* __restrict__ rp,
    const int* __restrict__ col, const float* __restrict__ b2,
    float* __restrict__ out, int N)
{
    __shared__ float4 ared[4][64];
    __shared__ float  sred[4][4];
    const int n    = blockIdx.x;
    const int t    = threadIdx.x;
    const int w    = t >> 6;
    const int lane = t & 63;
    const int head = lane >> 4;
    const int start = rp[n];
    const int d     = rp[n + 1] - start;
    const float adn = ad_[n * 4 + head];

    float ss = 0.f;
    float4 a0 = {0,0,0,0}, a1 = {0,0,0,0}, a2 = {0,0,0,0}, a3 = {0,0,0,0};

    int e = w;
    for (; e + 12 < d; e += 16) {
        const int s0 = col[start + e];
        const int s1 = col[start + e + 4];
        const int s2 = col[start + e + 8];
        const int s3 = col[start + e + 12];
        const float w0 = __expf(lrelu(as_[s0 * 4 + head] + adn));
        const float w1 = __expf(lrelu(as_[s1 * 4 + head] + adn));
        const float w2 = __expf(lrelu(as_[s2 * 4 + head] + adn));
        const float w3 = __expf(lrelu(as_[s3 * 4 + head] + adn));
        const uint2 u0 = *(const uint2*)(h16 + (size_t)s0 * 256 + 4 * lane);
        const uint2 u1 = *(const uint2*)(h16 + (size_t)s1 * 256 + 4 * lane);
        const uint2 u2 = *(const uint2*)(h16 + (size_t)s2 * 256 + 4 * lane);
        const uint2 u3 = *(const uint2*)(h16 + (size_t)s3 * 256 + 4 * lane);
        ss += (w0 + w1) + (w2 + w3);
        fma_row4(a0, w0, u0);
        fma_row4(a1, w1, u1);
        fma_row4(a2, w2, u2);
        fma_row4(a3, w3, u3);
    }
    for (; e < d; e += 4) {
        const int s = col[start + e];
        const float wt = __expf(lrelu(as_[s * 4 + head] + adn));
        const uint2 u = *(const uint2*)(h16 + (size_t)s * 256 + 4 * lane);
        ss += wt;
        fma_row4(a0, wt, u);
    }
    if (w == 0) {   // self-loop
        const float wt = __expf(lrelu(as_[n * 4 + head] + adn));
        const uint2 u = *(const uint2*)(h16 + (size_t)n * 256 + 4 * lane);
        ss += wt;
        fma_row4(a0, wt, u);
    }

    float4 at;
    at.x = (a0.x + a1.x) + (a2.x + a3.x);
    at.y = (a0.y + a1.y) + (a2.y + a3.y);
    at.z = (a0.z + a1.z) + (a2.z + a3.z);
    at.w = (a0.w + a1.w) + (a2.w + a3.w);
    ared[w][lane] = at;
    if ((lane & 15) == 0) sred[w][head] = ss;
    __syncthreads();

    if (t < 64) {
        float is[4];
        #pragma unroll
        for (int h = 0; h < 4; ++h)
            is[h] = 1.f / (sred[0][h] + sred[1][h] + sred[2][h] + sred[3][h] + GAT_EPS);
        const float* ap0 = (const float*)ared[0];
        const float* ap1 = (const float*)ared[1];
        const float* ap2 = (const float*)ared[2];
        const float* ap3 = (const float*)ared[3];
        float o = 0.f;
        #pragma unroll
        for (int h = 0; h < 4; ++h) {
            const int ch = h * 64 + t;
            o += ((ap0[ch] + ap1[ch]) + (ap2[ch] + ap3[ch])) * is[h];
        }
        out[(size_t)n * 64 + t] = 0.25f * o + b2[t];
    }
}

// ---------------------------------------------------------------------------
extern "C" void kernel_launch(void* const* d_in, const int* in_sizes, int n_in,
                              void* d_out, int out_size, void* d_ws, size_t ws_size,
                              hipStream_t stream)
{
    const float* x   = (const float*)d_in[0];
    const int*   ei  = (const int*)d_in[1];
    const float* W0  = (const float*)d_in[2];
    const float* aS0 = (const float*)d_in[3];
    const float* aD0 = (const float*)d_in[4];
    const float* b0  = (const float*)d_in[5];
    const float* W1  = (const float*)d_in[6];
    const float* aS1 = (const float*)d_in[7];
    const float* aD1 = (const float*)d_in[8];
    const float* b1  = (const float*)d_in[9];
    const float* W2  = (const float*)d_in[10];
    const float* aS2 = (const float*)d_in[11];
    const float* aD2 = (const float*)d_in[12];
    const float* b2  = (const float*)d_in[13];

    const int N = in_sizes[0] / 128;   // F_in = 128
    const int E = in_sizes[1] / 2;

    // Workspace layout (float units), ~82 MB:
    //   bufA [0,128N)      : fp32 h (layers 0/1) | fp16 h2 (layer 2, 256N halfs)
    //   bufA [128N,192N)   : fp16 h (layers 0/1, 128N halfs)
    //   o_buf [256N,384N)  : aggregated fp32 output of layers 0/1
    //   as/ad [384N,392N); rp/col/deg/bsum above
    float* ws     = (float*)d_ws;
    float* bufA   = ws;
    __half* h16a  = (__half*)(ws + (size_t)N * 128);
    __half* h2_16 = (__half*)ws;
    float* o_buf  = ws + (size_t)N * 256;
    float* as_buf = ws + (size_t)N * 384;
    float* ad_buf = ws + (size_t)N * 388;
    int*   rp     = (int*)(ws + (size_t)N * 392);
    int*   col    = (int*)(ws + (size_t)N * 394);
    int*   deg    = (int*)(ws + (size_t)N * 394) + E;
    int*   bsum   = deg + N;

    const int TB  = 256;
    const int gN  = (N + TB - 1) / TB;
    const int gE  = (E + TB - 1) / TB;
    const int gNH = (N * 4 + TB - 1) / TB;
    const int gS  = (N + 1023) / 1024;   // scan blocks (1024 elems each)

    // ---- build CSR (dst-sorted adjacency), shared by all 3 layers ----
    zero_kernel<<<gN, TB, 0, stream>>>(deg, N);
    count_kernel<<<gE, TB, 0, stream>>>(ei, deg, E);
    scan_part_kernel<<<gS, TB, 0, stream>>>(deg, bsum, N);
    scan_top_kernel<<<1, TB, 0, stream>>>(bsum, gS);
    scan_out_kernel<<<gS, TB, 0, stream>>>(deg, bsum, rp, N);
    scatter_kernel<<<gE, TB, 0, stream>>>(ei, rp, col, E);

    // ---- layer 0 ----
    {
        dim3 g((N + 63) / 64, 2);
        gemm_tiled<<<g, TB, 0, stream>>>(x, W0, bufA, h16a, N, 128, 128);
        alpha_kernel<<<gNH, TB, 0, stream>>>(bufA, aS0, aD0, as_buf, ad_buf, N, 128, 32);
        agg32_kernel<<<N, TB, 0, stream>>>(h16a, as_buf, ad_buf, rp, col, b0, o_buf, N);
    }
    // ---- layer 1 ----
    {
        dim3 g((N + 63) / 64, 2);
        gemm_tiled<<<g, TB, 0, stream>>>(o_buf, W1, bufA, h16a, N, 128, 128);
        alpha_kernel<<<gNH, TB, 0, stream>>>(bufA, aS1, aD1, as_buf, ad_buf, N, 128, 32);
        agg32_kernel<<<N, TB, 0, stream>>>(h16a, as_buf, ad_buf, rp, col, b1, o_buf, N);
    }
    // ---- layer 2 (concat=False): fp16-only h2; fused head-mean + bias -> d_out
    {
        dim3 g((N + 63) / 64, 4);
        gemm_tiled<<<g, TB, 0, stream>>>(o_buf, W2, nullptr, h2_16, N, 128, 256);
        alpha16_kernel<<<gNH, TB, 0, stream>>>(h2_16, aS2, aD2, as_buf, ad_buf, N, 256, 64);
        agg64_mean_kernel<<<N, TB, 0, stream>>>(h2_16, as_buf, ad_buf, rp, col, b2, (float*)d_out, N);
    }
}

// Round 11
// 517.639 us; speedup vs baseline: 1.5153x; 1.1738x over previous
//
#include <hip/hip_runtime.h>
#include <hip/hip_fp16.h>
#include <math.h>

#define NEG_SLOPE 0.2f
#define GAT_EPS 1e-16f

typedef _Float16 f16x8 __attribute__((ext_vector_type(8)));
typedef float    f32x4 __attribute__((ext_vector_type(4)));

__device__ __forceinline__ float lrelu(float x) { return x > 0.f ? x : NEG_SLOPE * x; }

__device__ __forceinline__ void fma_row4(float4& a, float w, uint2 u) {
    const float2 f0 = __half22float2(*(const __half2*)&u.x);
    const float2 f1 = __half22float2(*(const __half2*)&u.y);
    a.x += w * f0.x; a.y += w * f0.y;
    a.z += w * f1.x; a.w += w * f1.y;
}

__device__ __forceinline__ void fma_row2(float2& a, float w, unsigned u) {
    const float2 f = __half22float2(*(const __half2*)&u);
    a.x += w * f.x; a.y += w * f.y;
}

// ---------------------------------------------------------------------------
// fp32 tiled GEMM (layers 0/1). C fp32 + optional fp16 copy.
// ---------------------------------------------------------------------------
__global__ __launch_bounds__(256) void gemm_tiled(
    const float* __restrict__ A, const float* __restrict__ B,
    float* __restrict__ C, __half* __restrict__ C16, int M, int K, int Ncol)
{
    __shared__ float As[16][65];
    __shared__ float Bs[16][64];

    const int t  = threadIdx.x;
    const int bm = blockIdx.x * 64;
    const int bn = blockIdx.y * 64;
    const int tx = t & 15;
    const int ty = t >> 4;

    float acc[4][4] = {};

    for (int k0 = 0; k0 < K; k0 += 16) {
        {
            const int r  = t >> 2;
            const int kq = (t & 3) * 4;
            float4 v = make_float4(0.f, 0.f, 0.f, 0.f);
            const int row = bm + r;
            if (row < M) v = *(const float4*)(A + (size_t)row * K + k0 + kq);
            As[kq + 0][r] = v.x; As[kq + 1][r] = v.y;
            As[kq + 2][r] = v.z; As[kq + 3][r] = v.w;
        }
        {
            const int k  = t >> 4;
            const int nq = (t & 15) * 4;
            float4 v = *(const float4*)(B + (size_t)(k0 + k) * Ncol + bn + nq);
            *(float4*)(&Bs[k][nq]) = v;
        }
        __syncthreads();

        #pragma unroll
        for (int k = 0; k < 16; ++k) {
            float a[4], b[4];
            #pragma unroll
            for (int i = 0; i < 4; ++i) a[i] = As[k][ty * 4 + i];
            #pragma unroll
            for (int j = 0; j < 4; ++j) b[j] = Bs[k][tx * 4 + j];
            #pragma unroll
            for (int i = 0; i < 4; ++i)
                #pragma unroll
                for (int j = 0; j < 4; ++j)
                    acc[i][j] += a[i] * b[j];
        }
        __syncthreads();
    }

    #pragma unroll
    for (int i = 0; i < 4; ++i) {
        const int row = bm + ty * 4 + i;
        if (row < M) {
            #pragma unroll
            for (int j = 0; j < 4; ++j) {
                const float v = acc[i][j];
                const size_t idx = (size_t)row * Ncol + bn + tx * 4 + j;
                if (C)   C[idx]   = v;
                if (C16) C16[idx] = __float2half_rn(v);
            }
        }
    }
}

// ---------------------------------------------------------------------------
// Pack W2 (fp32 [128][256]) into fp16 MFMA B-fragment order:
// Wpk[((ks*256 + c)*4 + g)*8 + i] = W2[(ks*32 + g*8 + i)*256 + c]
// ---------------------------------------------------------------------------
__global__ __launch_bounds__(256) void pack_w2_kernel(
    const float* __restrict__ W2, __half* __restrict__ Wpk)
{
    const int idx = blockIdx.x * 256 + threadIdx.x;   // 128*256 = 32768
    const int k = idx >> 8;
    const int c = idx & 255;
    const int ks = k >> 5;
    const int g  = (k >> 3) & 3;
    const int i  = k & 7;
    Wpk[((size_t)(ks * 256 + c) * 4 + g) * 8 + i] = __float2half_rn(W2[idx]);
}

// ---------------------------------------------------------------------------
// Layer-2 GEMM via MFMA: h2[M,256] = A16[M,128] @ W2, fp16 in, fp32 acc,
// fp16 out. Block 256 = 4 waves; wave w: rows bm+16w..+15, cols bn..bn+63.
// A-frag: lane l -> row = l&15, k = ks*32 + (l>>4)*8 + i (contig 16B).
// B-frag: from packed Wpk (contig 16B). C/D: col=lane&15, row=(l>>4)*4+reg.
// ---------------------------------------------------------------------------
__global__ __launch_bounds__(256) void gemm2_mfma(
    const __half* __restrict__ A16, const __half* __restrict__ Wpk,
    __half* __restrict__ C16, int M)
{
    const int t  = threadIdx.x;
    const int w  = t >> 6;
    const int l  = t & 63;
    const int bm = blockIdx.x * 64;
    const int bn = blockIdx.y * 64;
    const int row = bm + w * 16 + (l & 15);
    const int kg  = l >> 4;
    const bool rok = row < M;

    f32x4 acc[4] = {};

    #pragma unroll
    for (int ks = 0; ks < 4; ++ks) {
        f16x8 a = {};
        if (rok)
            a = *(const f16x8*)(A16 + (size_t)row * 128 + ks * 32 + kg * 8);
        #pragma unroll
        for (int f = 0; f < 4; ++f) {
            const f16x8 b = *(const f16x8*)(Wpk +
                ((size_t)(ks * 256 + bn + f * 16 + (l & 15)) * 4 + kg) * 8);
            acc[f] = __builtin_amdgcn_mfma_f32_16x16x32_f16(a, b, acc[f], 0, 0, 0);
        }
    }

    const int orow = bm + w * 16 + (l >> 4) * 4;
    #pragma unroll
    for (int f = 0; f < 4; ++f) {
        const int ccol = bn + f * 16 + (l & 15);
        #pragma unroll
        for (int r = 0; r < 4; ++r) {
            if (orow + r < M)
                C16[(size_t)(orow + r) * 256 + ccol] = __float2half_rn(acc[f][r]);
        }
    }
}

// ---------------------------------------------------------------------------
// Per (node, head): alpha_src/dst dot products, fp32 h. H = 4.
// ---------------------------------------------------------------------------
__global__ __launch_bounds__(256) void alpha_kernel(
    const float* __restrict__ h, const float* __restrict__ a_src,
    const float* __restrict__ a_dst, float* __restrict__ as_,
    float* __restrict__ ad_, int N, int HC, int C)
{
    const int i = blockIdx.x * blockDim.x + threadIdx.x;
    if (i >= N * 4) return;
    const int n  = i >> 2;
    const int hh = i & 3;
    const float* hp  = h + (size_t)n * HC + hh * C;
    const float* asp = a_src + hh * C;
    const float* adp = a_dst + hh * C;
    float s1 = 0.f, s2 = 0.f;
    for (int c = 0; c < C; c += 4) {
        const float4 v = *(const float4*)(hp + c);
        const float4 A = *(const float4*)(asp + c);
        const float4 D = *(const float4*)(adp + c);
        s1 += v.x * A.x + v.y * A.y + v.z * A.z + v.w * A.w;
        s2 += v.x * D.x + v.y * D.y + v.z * D.z + v.w * D.w;
    }
    as_[i] = s1;
    ad_[i] = s2;
}

// Same, fp16 h (layer 2; C = 64).
__global__ __launch_bounds__(256) void alpha16_kernel(
    const __half* __restrict__ h, const float* __restrict__ a_src,
    const float* __restrict__ a_dst, float* __restrict__ as_,
    float* __restrict__ ad_, int N, int HC, int C)
{
    const int i = blockIdx.x * blockDim.x + threadIdx.x;
    if (i >= N * 4) return;
    const int n  = i >> 2;
    const int hh = i & 3;
    const __half* hp = h + (size_t)n * HC + hh * C;
    const float* asp = a_src + hh * C;
    const float* adp = a_dst + hh * C;
    float s1 = 0.f, s2 = 0.f;
    for (int c = 0; c < C; c += 2) {
        const float2 f = __half22float2(*(const __half2*)(hp + c));
        s1 += f.x * asp[c] + f.y * asp[c + 1];
        s2 += f.x * adp[c] + f.y * adp[c + 1];
    }
    as_[i] = s1;
    ad_[i] = s2;
}

// ---------------------------------------------------------------------------
// CSR build: zero -> count -> hierarchical scan -> scatter.
// ---------------------------------------------------------------------------
__global__ __launch_bounds__(256) void zero_kernel(int* __restrict__ p, int n)
{
    const int i = blockIdx.x * 256 + threadIdx.x;
    if (i < n) p[i] = 0;
}

__global__ __launch_bounds__(256) void count_kernel(
    const int* __restrict__ ei, int* __restrict__ deg, int E)
{
    const int e = blockIdx.x * 256 + threadIdx.x;
    if (e < E) atomicAdd(&deg[ei[E + e]], 1);
}

__global__ __launch_bounds__(256) void scan_part_kernel(
    const int* __restrict__ deg, int* __restrict__ bsum, int N)
{
    __shared__ int red[256];
    const int b = blockIdx.x;
    const int t = threadIdx.x;
    const int base = b * 1024 + t * 4;
    int s = 0;
    #pragma unroll
    for (int i = 0; i < 4; ++i) {
        const int idx = base + i;
        if (idx < N) s += deg[idx];
    }
    red[t] = s;
    __syncthreads();
    for (int off = 128; off; off >>= 1) {
        if (t < off) red[t] += red[t + off];
        __syncthreads();
    }
    if (t == 0) bsum[b] = red[0];
}

__global__ __launch_bounds__(256) void scan_top_kernel(
    int* __restrict__ bsum, int B)
{
    __shared__ int sh[256];
    const int t = threadIdx.x;
    const int v = (t < B) ? bsum[t] : 0;
    sh[t] = v;
    __syncthreads();
    for (int off = 1; off < 256; off <<= 1) {
        const int u = (t >= off) ? sh[t - off] : 0;
        __syncthreads();
        sh[t] += u;
        __syncthreads();
    }
    if (t < B) bsum[t] = sh[t] - v;   // exclusive
}

__global__ __launch_bounds__(256) void scan_out_kernel(
    const int* __restrict__ deg, const int* __restrict__ bsum,
    int* __restrict__ rp, int N)
{
    __shared__ int red[256];
    const int b = blockIdx.x;
    const int t = threadIdx.x;
    const int base = b * 1024 + t * 4;
    int v[4]; int s = 0;
    #pragma unroll
    for (int i = 0; i < 4; ++i) {
        const int idx = base + i;
        v[i] = (idx < N) ? deg[idx] : 0;
        s += v[i];
    }
    red[t] = s;
    __syncthreads();
    for (int off = 1; off < 256; off <<= 1) {
        const int u = (t >= off) ? red[t - off] : 0;
        __syncthreads();
        red[t] += u;
        __syncthreads();
    }
    int run = bsum[b] + ((t > 0) ? red[t - 1] : 0);
    if (b == 0 && t == 0) rp[0] = 0;
    #pragma unroll
    for (int i = 0; i < 4; ++i) {
        const int idx = base + i;
        if (idx < N) { rp[idx + 1] = run; run += v[i]; }
    }
}

__global__ __launch_bounds__(256) void scatter_kernel(
    const int* __restrict__ ei, int* __restrict__ rp, int* __restrict__ col, int E)
{
    const int e = blockIdx.x * 256 + threadIdx.x;
    if (e < E) {
        const int dn  = ei[E + e];
        const int pos = atomicAdd(&rp[dn + 1], 1);
        col[pos] = ei[e];
    }
}

// ---------------------------------------------------------------------------
// Fused softmax + aggregate, layers 0/1 (HC=128, C=32), bias+ReLU epilogue.
// ONE WAVE PER NODE (block = 4 waves = 4 nodes): no LDS, no syncthreads,
// ss needs no reduction (every lane sees every edge of its node).
// Lane covers channels {2l, 2l+1}; head = l>>4. 4 chains over d~16 edges.
// Optional fp16 output copy (feeds layer-2 MFMA).
// ---------------------------------------------------------------------------
__global__ __launch_bounds__(256) void agg32_kernel(
    const __half* __restrict__ h16, const float* __restrict__ as_,
    const float* __restrict__ ad_, const int* __restrict__ rp,
    const int* __restrict__ col, const float* __restrict__ bias,
    float* __restrict__ out, __half* __restrict__ out16, int N)
{
    const int n = blockIdx.x * 4 + (threadIdx.x >> 6);
    if (n >= N) return;
    const int lane = threadIdx.x & 63;
    const int head = lane >> 4;
    const int start = rp[n];
    const int d     = rp[n + 1] - start;
    const float adn = ad_[n * 4 + head];

    float ss = 0.f;
    float2 a0 = {0.f, 0.f}, a1 = {0.f, 0.f}, a2 = {0.f, 0.f}, a3 = {0.f, 0.f};

    int e = 0;
    for (; e + 4 <= d; e += 4) {
        const int s0 = col[start + e + 0];
        const int s1 = col[start + e + 1];
        const int s2 = col[start + e + 2];
        const int s3 = col[start + e + 3];
        const float w0 = __expf(lrelu(as_[s0 * 4 + head] + adn));
        const float w1 = __expf(lrelu(as_[s1 * 4 + head] + adn));
        const float w2 = __expf(lrelu(as_[s2 * 4 + head] + adn));
        const float w3 = __expf(lrelu(as_[s3 * 4 + head] + adn));
        const unsigned u0 = *(const unsigned*)(h16 + (size_t)s0 * 128 + 2 * lane);
        const unsigned u1 = *(const unsigned*)(h16 + (size_t)s1 * 128 + 2 * lane);
        const unsigned u2 = *(const unsigned*)(h16 + (size_t)s2 * 128 + 2 * lane);
        const unsigned u3 = *(const unsigned*)(h16 + (size_t)s3 * 128 + 2 * lane);
        ss += (w0 + w1) + (w2 + w3);
        fma_row2(a0, w0, u0);
        fma_row2(a1, w1, u1);
        fma_row2(a2, w2, u2);
        fma_row2(a3, w3, u3);
    }
    for (; e < d; ++e) {
        const int s = col[start + e];
        const float wt = __expf(lrelu(as_[s * 4 + head] + adn));
        const unsigned u = *(const unsigned*)(h16 + (size_t)s * 128 + 2 * lane);
        ss += wt;
        fma_row2(a0, wt, u);
    }
    // self-loop
    {
        const float wt = __expf(lrelu(as_[n * 4 + head] + adn));
        const unsigned u = *(const unsigned*)(h16 + (size_t)n * 128 + 2 * lane);
        ss += wt;
        fma_row2(a0, wt, u);
    }

    float2 v;
    v.x = (a0.x + a1.x) + (a2.x + a3.x);
    v.y = (a0.y + a1.y) + (a2.y + a3.y);
    const float inv = 1.f / (ss + GAT_EPS);
    const float2 bb = *(const float2*)(bias + 2 * lane);
    v.x = fmaxf(v.x * inv + bb.x, 0.f);
    v.y = fmaxf(v.y * inv + bb.y, 0.f);
    *(float2*)(out + (size_t)n * 128 + 2 * lane) = v;
    if (out16)
        *(__half2*)(out16 + (size_t)n * 128 + 2 * lane) = __floats2half2_rn(v.x, v.y);
}

// ---------------------------------------------------------------------------
// Fused softmax + aggregate + head-mean + bias, layer 2 (HC=256, C=64).
// One wave per node; lane covers channels {4l..4l+3}; head = l>>4.
// Head-mean via shfl_xor(16/32); lanes 0-15 write the 64-float output row.
// ---------------------------------------------------------------------------
__global__ __launch_bounds__(256) void agg64_mean_kernel(
    const __half* __restrict__ h16, const float* __restrict__ as_,
    const float* __restrict__ ad_, const int* __restrict__ rp,
    const int* __restrict__ col, const float* __restrict__ b2,
    float* __restrict__ out, int N)
{
    const int n = blockIdx.x * 4 + (threadIdx.x >> 6);
    if (n >= N) return;
    const int lane = threadIdx.x & 63;
    const int head = lane >> 4;
    const int start = rp[n];
    const int d     = rp[n + 1] - start;
    const float adn = ad_[n * 4 + head];

    float ss = 0.f;
    float4 a0 = {0,0,0,0}, a1 = {0,0,0,0}, a2 = {0,0,0,0}, a3 = {0,0,0,0};

    int e = 0;
    for (; e + 4 <= d; e += 4) {
        const int s0 = col[start + e + 0];
        const int s1 = col[start + e + 1];
        const int s2 = col[start + e + 2];
        const int s3 = col[start + e + 3];
        const float w0 = __expf(lrelu(as_[s0 * 4 + head] + adn));
        const float w1 = __expf(lrelu(as_[s1 * 4 + head] + adn));
        const float w2 = __expf(lrelu(as_[s2 * 4 + head] + adn));
        const float w3 = __expf(lrelu(as_[s3 * 4 + head] + adn));
        const uint2 u0 = *(const uint2*)(h16 + (size_t)s0 * 256 + 4 * lane);
        const uint2 u1 = *(const uint2*)(h16 + (size_t)s1 * 256 + 4 * lane);
        const uint2 u2 = *(const uint2*)(h16 + (size_t)s2 * 256 + 4 * lane);
        const uint2 u3 = *(const uint2*)(h16 + (size_t)s3 * 256 + 4 * lane);
        ss += (w0 + w1) + (w2 + w3);
        fma_row4(a0, w0, u0);
        fma_row4(a1, w1, u1);
        fma_row4(a2, w2, u2);
        fma_row4(a3, w3, u3);
    }
    for (; e < d; ++e) {
        const int s = col[start + e];
        const float wt = __expf(lrelu(as_[s * 4 + head] + adn));
        const uint2 u = *(const uint2*)(h16 + (size_t)s * 256 + 4 * lane);
        ss += wt;
        fma_row4(a0, wt, u);
    }
    // self-loop
    {
        const float wt = __expf(lrelu(as_[n * 4 + head] + adn));
        const uint2 u = *(const uint2*)(h16 + (size_t)n * 256 + 4 * lane);
        ss += wt;
        fma_row4(a0, wt, u);
    }

    const float inv = 1.f / (ss + GAT_EPS);
    float vx = ((a0.x + a1.x) + (a2.x + a3.x)) * inv;
    float vy = ((a0.y + a1.y) + (a2.y + a3.y)) * inv;
    float vz = ((a0.z + a1.z) + (a2.z + a3.z)) * inv;
    float vw = ((a0.w + a1.w) + (a2.w + a3.w)) * inv;

    // head-mean: sum across lanes differing in bits 4,5 (the head bits)
    vx += __shfl_xor(vx, 16); vx += __shfl_xor(vx, 32);
    vy += __shfl_xor(vy, 16); vy += __shfl_xor(vy, 32);
    vz += __shfl_xor(vz, 16); vz += __shfl_xor(vz, 32);
    vw += __shfl_xor(vw, 16); vw += __shfl_xor(vw, 32);

    if (lane < 16) {
        const float4 bb = *(const float4*)(b2 + 4 * lane);
        float4 o;
        o.x = 0.25f * vx + bb.x;
        o.y = 0.25f * vy + bb.y;
        o.z = 0.25f * vz + bb.z;
        o.w = 0.25f * vw + bb.w;
        *(float4*)(out + (size_t)n * 64 + 4 * lane) = o;
    }
}

// ---------------------------------------------------------------------------
extern "C" void kernel_launch(void* const* d_in, const int* in_sizes, int n_in,
                              void* d_out, int out_size, void* d_ws, size_t ws_size,
                              hipStream_t stream)
{
    const float* x   = (const float*)d_in[0];
    const int*   ei  = (const int*)d_in[1];
    const float* W0  = (const float*)d_in[2];
    const float* aS0 = (const float*)d_in[3];
    const float* aD0 = (const float*)d_in[4];
    const float* b0  = (const float*)d_in[5];
    const float* W1  = (const float*)d_in[6];
    const float* aS1 = (const float*)d_in[7];
    const float* aD1 = (const float*)d_in[8];
    const float* b1  = (const float*)d_in[9];
    const float* W2  = (const float*)d_in[10];
    const float* aS2 = (const float*)d_in[11];
    const float* aD2 = (const float*)d_in[12];
    const float* b2  = (const float*)d_in[13];

    const int N = in_sizes[0] / 128;   // F_in = 128
    const int E = in_sizes[1] / 2;

    // Workspace (float units), ~82 MB:
    //   bufA  [0,128N)      : fp32 h (layers 0/1) | fp16 h2 (layer 2, 256N halfs)
    //   h16a  [128N,192N)   : fp16 h (layers 0/1)
    //   o16   [192N,256N)   : fp16 copy of layer-1 output (MFMA A operand)
    //   o_buf [256N,384N)   : fp32 aggregated output of layers 0/1
    //   as/ad [384N,392N); rp/col/deg/bsum/Wpk above
    float* ws     = (float*)d_ws;
    float* bufA   = ws;
    __half* h16a  = (__half*)(ws + (size_t)N * 128);
    __half* o16   = (__half*)(ws + (size_t)N * 192);
    __half* h2_16 = (__half*)ws;
    float* o_buf  = ws + (size_t)N * 256;
    float* as_buf = ws + (size_t)N * 384;
    float* ad_buf = ws + (size_t)N * 388;
    int*   rp     = (int*)(ws + (size_t)N * 392);
    int*   col    = (int*)(ws + (size_t)N * 394);
    int*   deg    = (int*)(ws + (size_t)N * 394) + E;
    int*   bsum   = deg + N;
    __half* Wpk   = (__half*)(bsum + 256);         // 32768 halves (64 KB)

    const int TB  = 256;
    const int gN  = (N + TB - 1) / TB;
    const int gE  = (E + TB - 1) / TB;
    const int gNH = (N * 4 + TB - 1) / TB;
    const int gS  = (N + 1023) / 1024;
    const int gA  = (N + 3) / 4;                    // agg blocks (4 nodes each)

    // ---- CSR build + W2 packing (independent prep) ----
    zero_kernel<<<gN, TB, 0, stream>>>(deg, N);
    count_kernel<<<gE, TB, 0, stream>>>(ei, deg, E);
    pack_w2_kernel<<<128, TB, 0, stream>>>(W2, Wpk);
    scan_part_kernel<<<gS, TB, 0, stream>>>(deg, bsum, N);
    scan_top_kernel<<<1, TB, 0, stream>>>(bsum, gS);
    scan_out_kernel<<<gS, TB, 0, stream>>>(deg, bsum, rp, N);
    scatter_kernel<<<gE, TB, 0, stream>>>(ei, rp, col, E);

    // ---- layer 0 ----
    {
        dim3 g((N + 63) / 64, 2);
        gemm_tiled<<<g, TB, 0, stream>>>(x, W0, bufA, h16a, N, 128, 128);
        alpha_kernel<<<gNH, TB, 0, stream>>>(bufA, aS0, aD0, as_buf, ad_buf, N, 128, 32);
        agg32_kernel<<<gA, TB, 0, stream>>>(h16a, as_buf, ad_buf, rp, col, b0, o_buf, nullptr, N);
    }
    // ---- layer 1 (emits fp16 output copy for the MFMA) ----
    {
        dim3 g((N + 63) / 64, 2);
        gemm_tiled<<<g, TB, 0, stream>>>(o_buf, W1, bufA, h16a, N, 128, 128);
        alpha_kernel<<<gNH, TB, 0, stream>>>(bufA, aS1, aD1, as_buf, ad_buf, N, 128, 32);
        agg32_kernel<<<gA, TB, 0, stream>>>(h16a, as_buf, ad_buf, rp, col, b1, o_buf, o16, N);
    }
    // ---- layer 2: fp16 MFMA GEMM -> fp16 h2; fused head-mean + bias -> d_out
    {
        dim3 g((N + 63) / 64, 4);
        gemm2_mfma<<<g, TB, 0, stream>>>(o16, Wpk, h2_16, N);
        alpha16_kernel<<<gNH, TB, 0, stream>>>(h2_16, aS2, aD2, as_buf, ad_buf, N, 256, 64);
        agg64_mean_kernel<<<gA, TB, 0, stream>>>(h2_16, as_buf, ad_buf, rp, col, b2, (float*)d_out, N);
    }
}

// Round 12
// 505.717 us; speedup vs baseline: 1.5510x; 1.0236x over previous
//
#include <hip/hip_runtime.h>
#include <hip/hip_fp16.h>
#include <math.h>

#define NEG_SLOPE 0.2f
#define GAT_EPS 1e-16f

typedef _Float16 f16x8 __attribute__((ext_vector_type(8)));
typedef float    f32x4 __attribute__((ext_vector_type(4)));

__device__ __forceinline__ float lrelu(float x) { return x > 0.f ? x : NEG_SLOPE * x; }

__device__ __forceinline__ void fma_row4(float4& a, float w, uint2 u) {
    const float2 f0 = __half22float2(*(const __half2*)&u.x);
    const float2 f1 = __half22float2(*(const __half2*)&u.y);
    a.x += w * f0.x; a.y += w * f0.y;
    a.z += w * f1.x; a.w += w * f1.y;
}

__device__ __forceinline__ void fma_row2(float2& a, float w, unsigned u) {
    const float2 f = __half22float2(*(const __half2*)&u);
    a.x += w * f.x; a.y += w * f.y;
}

// ---------------------------------------------------------------------------
// fp32 -> fp16 cast (x input), 2 elems/thread
// ---------------------------------------------------------------------------
__global__ __launch_bounds__(256) void cast16_kernel(
    const float* __restrict__ src, __half* __restrict__ dst, int n2)
{
    const int i = blockIdx.x * 256 + threadIdx.x;
    if (i < n2) {
        const float2 v = *(const float2*)(src + 2 * i);
        *(__half2*)(dst + 2 * i) = __floats2half2_rn(v.x, v.y);
    }
}

// ---------------------------------------------------------------------------
// Pack W (fp32 [128][Ncol]) into fp16 MFMA B-fragment order:
// Wpk[((ks*Ncol + c)*4 + g)*8 + i] = W[(ks*32 + g*8 + i)*Ncol + c]
// ---------------------------------------------------------------------------
__global__ __launch_bounds__(256) void pack_w_kernel(
    const float* __restrict__ W, __half* __restrict__ Wpk, int Ncol)
{
    const int idx = blockIdx.x * 256 + threadIdx.x;   // 128*Ncol
    const int k = idx / Ncol;
    const int c = idx - k * Ncol;
    const int ks = k >> 5;
    const int g  = (k >> 3) & 3;
    const int i  = k & 7;
    Wpk[((size_t)(ks * Ncol + c) * 4 + g) * 8 + i] = __float2half_rn(W[idx]);
}

// ---------------------------------------------------------------------------
// MFMA GEMM: C16[M,Ncol] = A16[M,128] @ W (packed), fp16 in, fp32 acc,
// fp16 out. Block 256 = 4 waves; wave w: rows bm+16w..+15, cols bn..bn+63.
// A-frag: lane l -> row = l&15, k = ks*32 + (l>>4)*8 + i (contig 16B).
// B-frag: packed Wpk (contig 16B). C/D: col=lane&15, row=(l>>4)*4+reg.
// (Layout HW-verified in R11: absmax unchanged vs fp32 GEMM.)
// ---------------------------------------------------------------------------
__global__ __launch_bounds__(256) void gemm_mfma(
    const __half* __restrict__ A16, const __half* __restrict__ Wpk,
    __half* __restrict__ C16, int M, int Ncol)
{
    const int t  = threadIdx.x;
    const int w  = t >> 6;
    const int l  = t & 63;
    const int bm = blockIdx.x * 64;
    const int bn = blockIdx.y * 64;
    const int row = bm + w * 16 + (l & 15);
    const int kg  = l >> 4;
    const bool rok = row < M;

    f32x4 acc[4] = {};

    #pragma unroll
    for (int ks = 0; ks < 4; ++ks) {
        f16x8 a = {};
        if (rok)
            a = *(const f16x8*)(A16 + (size_t)row * 128 + ks * 32 + kg * 8);
        #pragma unroll
        for (int f = 0; f < 4; ++f) {
            const f16x8 b = *(const f16x8*)(Wpk +
                ((size_t)(ks * Ncol + bn + f * 16 + (l & 15)) * 4 + kg) * 8);
            acc[f] = __builtin_amdgcn_mfma_f32_16x16x32_f16(a, b, acc[f], 0, 0, 0);
        }
    }

    const int orow = bm + w * 16 + (l >> 4) * 4;
    #pragma unroll
    for (int f = 0; f < 4; ++f) {
        const int ccol = bn + f * 16 + (l & 15);
        #pragma unroll
        for (int r = 0; r < 4; ++r) {
            if (orow + r < M)
                C16[(size_t)(orow + r) * Ncol + ccol] = __float2half_rn(acc[f][r]);
        }
    }
}

// ---------------------------------------------------------------------------
// Per (node, head): alpha_src/dst dot products, fp16 h. H = 4.
// ---------------------------------------------------------------------------
__global__ __launch_bounds__(256) void alpha16_kernel(
    const __half* __restrict__ h, const float* __restrict__ a_src,
    const float* __restrict__ a_dst, float* __restrict__ as_,
    float* __restrict__ ad_, int N, int HC, int C)
{
    const int i = blockIdx.x * blockDim.x + threadIdx.x;
    if (i >= N * 4) return;
    const int n  = i >> 2;
    const int hh = i & 3;
    const __half* hp = h + (size_t)n * HC + hh * C;
    const float* asp = a_src + hh * C;
    const float* adp = a_dst + hh * C;
    float s1 = 0.f, s2 = 0.f;
    for (int c = 0; c < C; c += 2) {
        const float2 f = __half22float2(*(const __half2*)(hp + c));
        s1 += f.x * asp[c] + f.y * asp[c + 1];
        s2 += f.x * adp[c] + f.y * adp[c + 1];
    }
    as_[i] = s1;
    ad_[i] = s2;
}

// ---------------------------------------------------------------------------
// CSR build: zero -> count -> hierarchical scan -> scatter.
// ---------------------------------------------------------------------------
__global__ __launch_bounds__(256) void zero_kernel(int* __restrict__ p, int n)
{
    const int i = blockIdx.x * 256 + threadIdx.x;
    if (i < n) p[i] = 0;
}

__global__ __launch_bounds__(256) void count_kernel(
    const int* __restrict__ ei, int* __restrict__ deg, int E)
{
    const int e = blockIdx.x * 256 + threadIdx.x;
    if (e < E) atomicAdd(&deg[ei[E + e]], 1);
}

__global__ __launch_bounds__(256) void scan_part_kernel(
    const int* __restrict__ deg, int* __restrict__ bsum, int N)
{
    __shared__ int red[256];
    const int b = blockIdx.x;
    const int t = threadIdx.x;
    const int base = b * 1024 + t * 4;
    int s = 0;
    #pragma unroll
    for (int i = 0; i < 4; ++i) {
        const int idx = base + i;
        if (idx < N) s += deg[idx];
    }
    red[t] = s;
    __syncthreads();
    for (int off = 128; off; off >>= 1) {
        if (t < off) red[t] += red[t + off];
        __syncthreads();
    }
    if (t == 0) bsum[b] = red[0];
}

__global__ __launch_bounds__(256) void scan_top_kernel(
    int* __restrict__ bsum, int B)
{
    __shared__ int sh[256];
    const int t = threadIdx.x;
    const int v = (t < B) ? bsum[t] : 0;
    sh[t] = v;
    __syncthreads();
    for (int off = 1; off < 256; off <<= 1) {
        const int u = (t >= off) ? sh[t - off] : 0;
        __syncthreads();
        sh[t] += u;
        __syncthreads();
    }
    if (t < B) bsum[t] = sh[t] - v;   // exclusive
}

__global__ __launch_bounds__(256) void scan_out_kernel(
    const int* __restrict__ deg, const int* __restrict__ bsum,
    int* __restrict__ rp, int N)
{
    __shared__ int red[256];
    const int b = blockIdx.x;
    const int t = threadIdx.x;
    const int base = b * 1024 + t * 4;
    int v[4]; int s = 0;
    #pragma unroll
    for (int i = 0; i < 4; ++i) {
        const int idx = base + i;
        v[i] = (idx < N) ? deg[idx] : 0;
        s += v[i];
    }
    red[t] = s;
    __syncthreads();
    for (int off = 1; off < 256; off <<= 1) {
        const int u = (t >= off) ? red[t - off] : 0;
        __syncthreads();
        red[t] += u;
        __syncthreads();
    }
    int run = bsum[b] + ((t > 0) ? red[t - 1] : 0);
    if (b == 0 && t == 0) rp[0] = 0;
    #pragma unroll
    for (int i = 0; i < 4; ++i) {
        const int idx = base + i;
        if (idx < N) { rp[idx + 1] = run; run += v[i]; }
    }
}

__global__ __launch_bounds__(256) void scatter_kernel(
    const int* __restrict__ ei, int* __restrict__ rp, int* __restrict__ col, int E)
{
    const int e = blockIdx.x * 256 + threadIdx.x;
    if (e < E) {
        const int dn  = ei[E + e];
        const int pos = atomicAdd(&rp[dn + 1], 1);
        col[pos] = ei[e];
    }
}

// ---------------------------------------------------------------------------
// Fused softmax + aggregate, layers 0/1 (HC=128, C=32), bias+ReLU epilogue.
// ONE WAVE PER NODE (block = 4 waves = 4 nodes). fp16 in, fp16 out.
// Lane covers channels {2l, 2l+1}; head = l>>4. 4 chains over d~16 edges.
// ---------------------------------------------------------------------------
__global__ __launch_bounds__(256) void agg32_kernel(
    const __half* __restrict__ h16, const float* __restrict__ as_,
    const float* __restrict__ ad_, const int* __restrict__ rp,
    const int* __restrict__ col, const float* __restrict__ bias,
    __half* __restrict__ out16, int N)
{
    const int n = blockIdx.x * 4 + (threadIdx.x >> 6);
    if (n >= N) return;
    const int lane = threadIdx.x & 63;
    const int head = lane >> 4;
    const int start = rp[n];
    const int d     = rp[n + 1] - start;
    const float adn = ad_[n * 4 + head];

    float ss = 0.f;
    float2 a0 = {0.f, 0.f}, a1 = {0.f, 0.f}, a2 = {0.f, 0.f}, a3 = {0.f, 0.f};

    int e = 0;
    for (; e + 4 <= d; e += 4) {
        const int s0 = col[start + e + 0];
        const int s1 = col[start + e + 1];
        const int s2 = col[start + e + 2];
        const int s3 = col[start + e + 3];
        const float w0 = __expf(lrelu(as_[s0 * 4 + head] + adn));
        const float w1 = __expf(lrelu(as_[s1 * 4 + head] + adn));
        const float w2 = __expf(lrelu(as_[s2 * 4 + head] + adn));
        const float w3 = __expf(lrelu(as_[s3 * 4 + head] + adn));
        const unsigned u0 = *(const unsigned*)(h16 + (size_t)s0 * 128 + 2 * lane);
        const unsigned u1 = *(const unsigned*)(h16 + (size_t)s1 * 128 + 2 * lane);
        const unsigned u2 = *(const unsigned*)(h16 + (size_t)s2 * 128 + 2 * lane);
        const unsigned u3 = *(const unsigned*)(h16 + (size_t)s3 * 128 + 2 * lane);
        ss += (w0 + w1) + (w2 + w3);
        fma_row2(a0, w0, u0);
        fma_row2(a1, w1, u1);
        fma_row2(a2, w2, u2);
        fma_row2(a3, w3, u3);
    }
    for (; e < d; ++e) {
        const int s = col[start + e];
        const float wt = __expf(lrelu(as_[s * 4 + head] + adn));
        const unsigned u = *(const unsigned*)(h16 + (size_t)s * 128 + 2 * lane);
        ss += wt;
        fma_row2(a0, wt, u);
    }
    // self-loop
    {
        const float wt = __expf(lrelu(as_[n * 4 + head] + adn));
        const unsigned u = *(const unsigned*)(h16 + (size_t)n * 128 + 2 * lane);
        ss += wt;
        fma_row2(a0, wt, u);
    }

    float2 v;
    v.x = (a0.x + a1.x) + (a2.x + a3.x);
    v.y = (a0.y + a1.y) + (a2.y + a3.y);
    const float inv = 1.f / (ss + GAT_EPS);
    const float2 bb = *(const float2*)(bias + 2 * lane);
    v.x = fmaxf(v.x * inv + bb.x, 0.f);
    v.y = fmaxf(v.y * inv + bb.y, 0.f);
    *(__half2*)(out16 + (size_t)n * 128 + 2 * lane) = __floats2half2_rn(v.x, v.y);
}

// ---------------------------------------------------------------------------
// Fused softmax + aggregate + head-mean + bias, layer 2 (HC=256, C=64).
// One wave per node; lane covers channels {4l..4l+3}; head = l>>4.
// ---------------------------------------------------------------------------
__global__ __launch_bounds__(256) void agg64_mean_kernel(
    const __half* __restrict__ h16, const float* __restrict__ as_,
    const float* __restrict__ ad_, const int* __restrict__ rp,
    const int* __restrict__ col, const float* __restrict__ b2,
    float* __restrict__ out, int N)
{
    const int n = blockIdx.x * 4 + (threadIdx.x >> 6);
    if (n >= N) return;
    const int lane = threadIdx.x & 63;
    const int head = lane >> 4;
    const int start = rp[n];
    const int d     = rp[n + 1] - start;
    const float adn = ad_[n * 4 + head];

    float ss = 0.f;
    float4 a0 = {0,0,0,0}, a1 = {0,0,0,0}, a2 = {0,0,0,0}, a3 = {0,0,0,0};

    int e = 0;
    for (; e + 4 <= d; e += 4) {
        const int s0 = col[start + e + 0];
        const int s1 = col[start + e + 1];
        const int s2 = col[start + e + 2];
        const int s3 = col[start + e + 3];
        const float w0 = __expf(lrelu(as_[s0 * 4 + head] + adn));
        const float w1 = __expf(lrelu(as_[s1 * 4 + head] + adn));
        const float w2 = __expf(lrelu(as_[s2 * 4 + head] + adn));
        const float w3 = __expf(lrelu(as_[s3 * 4 + head] + adn));
        const uint2 u0 = *(const uint2*)(h16 + (size_t)s0 * 256 + 4 * lane);
        const uint2 u1 = *(const uint2*)(h16 + (size_t)s1 * 256 + 4 * lane);
        const uint2 u2 = *(const uint2*)(h16 + (size_t)s2 * 256 + 4 * lane);
        const uint2 u3 = *(const uint2*)(h16 + (size_t)s3 * 256 + 4 * lane);
        ss += (w0 + w1) + (w2 + w3);
        fma_row4(a0, w0, u0);
        fma_row4(a1, w1, u1);
        fma_row4(a2, w2, u2);
        fma_row4(a3, w3, u3);
    }
    for (; e < d; ++e) {
        const int s = col[start + e];
        const float wt = __expf(lrelu(as_[s * 4 + head] + adn));
        const uint2 u = *(const uint2*)(h16 + (size_t)s * 256 + 4 * lane);
        ss += wt;
        fma_row4(a0, wt, u);
    }
    // self-loop
    {
        const float wt = __expf(lrelu(as_[n * 4 + head] + adn));
        const uint2 u = *(const uint2*)(h16 + (size_t)n * 256 + 4 * lane);
        ss += wt;
        fma_row4(a0, wt, u);
    }

    const float inv = 1.f / (ss + GAT_EPS);
    float vx = ((a0.x + a1.x) + (a2.x + a3.x)) * inv;
    float vy = ((a0.y + a1.y) + (a2.y + a3.y)) * inv;
    float vz = ((a0.z + a1.z) + (a2.z + a3.z)) * inv;
    float vw = ((a0.w + a1.w) + (a2.w + a3.w)) * inv;

    vx += __shfl_xor(vx, 16); vx += __shfl_xor(vx, 32);
    vy += __shfl_xor(vy, 16); vy += __shfl_xor(vy, 32);
    vz += __shfl_xor(vz, 16); vz += __shfl_xor(vz, 32);
    vw += __shfl_xor(vw, 16); vw += __shfl_xor(vw, 32);

    if (lane < 16) {
        const float4 bb = *(const float4*)(b2 + 4 * lane);
        float4 o;
        o.x = 0.25f * vx + bb.x;
        o.y = 0.25f * vy + bb.y;
        o.z = 0.25f * vz + bb.z;
        o.w = 0.25f * vw + bb.w;
        *(float4*)(out + (size_t)n * 64 + 4 * lane) = o;
    }
}

// ---------------------------------------------------------------------------
extern "C" void kernel_launch(void* const* d_in, const int* in_sizes, int n_in,
                              void* d_out, int out_size, void* d_ws, size_t ws_size,
                              hipStream_t stream)
{
    const float* x   = (const float*)d_in[0];
    const int*   ei  = (const int*)d_in[1];
    const float* W0  = (const float*)d_in[2];
    const float* aS0 = (const float*)d_in[3];
    const float* aD0 = (const float*)d_in[4];
    const float* b0  = (const float*)d_in[5];
    const float* W1  = (const float*)d_in[6];
    const float* aS1 = (const float*)d_in[7];
    const float* aD1 = (const float*)d_in[8];
    const float* b1  = (const float*)d_in[9];
    const float* W2  = (const float*)d_in[10];
    const float* aS2 = (const float*)d_in[11];
    const float* aD2 = (const float*)d_in[12];
    const float* b2  = (const float*)d_in[13];

    const int N = in_sizes[0] / 128;   // F_in = 128
    const int E = in_sizes[1] / 2;

    // Workspace (float units), ~57 MB:
    //   h2_16 [0,128N)      : fp16 h2 (layer 2, 256N halfs)
    //   h16   [128N,192N)   : fp16 GEMM output h (layers 0/1)
    //   a16   [192N,256N)   : fp16 GEMM A operand (x16 / layer-0 out / layer-1 out)
    //   as/ad [256N,264N)
    //   rp/col/deg/bsum/Wpk above
    float* ws     = (float*)d_ws;
    __half* h2_16 = (__half*)ws;
    __half* h16   = (__half*)(ws + (size_t)N * 128);
    __half* a16   = (__half*)(ws + (size_t)N * 192);
    float* as_buf = ws + (size_t)N * 256;
    float* ad_buf = ws + (size_t)N * 260;
    int*   rp     = (int*)(ws + (size_t)N * 264);
    int*   col    = (int*)(ws + (size_t)N * 266);
    int*   deg    = (int*)(ws + (size_t)N * 266) + E;
    int*   bsum   = deg + N;
    __half* Wpk0  = (__half*)(bsum + 256);          // 16384 halves
    __half* Wpk1  = Wpk0 + 16384;                   // 16384 halves
    __half* Wpk2  = Wpk1 + 16384;                   // 32768 halves

    const int TB  = 256;
    const int gN  = (N + TB - 1) / TB;
    const int gE  = (E + TB - 1) / TB;
    const int gNH = (N * 4 + TB - 1) / TB;
    const int gS  = (N + 1023) / 1024;
    const int gA  = (N + 3) / 4;

    // ---- prep: CSR build + weight packing + x cast ----
    zero_kernel<<<gN, TB, 0, stream>>>(deg, N);
    count_kernel<<<gE, TB, 0, stream>>>(ei, deg, E);
    pack_w_kernel<<<64, TB, 0, stream>>>(W0, Wpk0, 128);
    pack_w_kernel<<<64, TB, 0, stream>>>(W1, Wpk1, 128);
    pack_w_kernel<<<128, TB, 0, stream>>>(W2, Wpk2, 256);
    cast16_kernel<<<(N * 64 + TB - 1) / TB, TB, 0, stream>>>(x, a16, N * 64);
    scan_part_kernel<<<gS, TB, 0, stream>>>(deg, bsum, N);
    scan_top_kernel<<<1, TB, 0, stream>>>(bsum, gS);
    scan_out_kernel<<<gS, TB, 0, stream>>>(deg, bsum, rp, N);
    scatter_kernel<<<gE, TB, 0, stream>>>(ei, rp, col, E);

    // ---- layer 0 ----
    {
        dim3 g((N + 63) / 64, 2);
        gemm_mfma<<<g, TB, 0, stream>>>(a16, Wpk0, h16, N, 128);
        alpha16_kernel<<<gNH, TB, 0, stream>>>(h16, aS0, aD0, as_buf, ad_buf, N, 128, 32);
        agg32_kernel<<<gA, TB, 0, stream>>>(h16, as_buf, ad_buf, rp, col, b0, a16, N);
    }
    // ---- layer 1 ----
    {
        dim3 g((N + 63) / 64, 2);
        gemm_mfma<<<g, TB, 0, stream>>>(a16, Wpk1, h16, N, 128);
        alpha16_kernel<<<gNH, TB, 0, stream>>>(h16, aS1, aD1, as_buf, ad_buf, N, 128, 32);
        agg32_kernel<<<gA, TB, 0, stream>>>(h16, as_buf, ad_buf, rp, col, b1, a16, N);
    }
    // ---- layer 2: MFMA -> fp16 h2; fused head-mean + bias -> d_out ----
    {
        dim3 g((N + 63) / 64, 4);
        gemm_mfma<<<g, TB, 0, stream>>>(a16, Wpk2, h2_16, N, 256);
        alpha16_kernel<<<gNH, TB, 0, stream>>>(h2_16, aS2, aD2, as_buf, ad_buf, N, 256, 64);
        agg64_mean_kernel<<<gA, TB, 0, stream>>>(h2_16, as_buf, ad_buf, rp, col, b2, (float*)d_out, N);
    }
}